// Round 1
// baseline (629.666 us; speedup 1.0000x reference)
//
#include <hip/hip_runtime.h>

#define TOK   16384   // B*T
#define DIM_  1024
#define QKV_N 3072
#define NH    16
#define HD    64
#define NF    256
#define TSEQ  4096
#define NCHUNK 8
#define CH_T  512     // TSEQ/NCHUNK
#define KVS   68      // kv row stride (64 d + 1 ksum + pad)

typedef __attribute__((ext_vector_type(8))) short  bfrag8;   // 8 bf16 (4 VGPRs)
typedef __attribute__((ext_vector_type(4))) float  ffrag4;   // 4 fp32 acc
typedef __attribute__((ext_vector_type(8))) unsigned short u16x8;
typedef __attribute__((ext_vector_type(4))) unsigned short u16x4;

__device__ __forceinline__ float bf2f(unsigned short u) {
  union { unsigned int i; float f; } c; c.i = ((unsigned int)u) << 16; return c.f;
}
__device__ __forceinline__ unsigned short f2bf(float f) {
  union { float f; unsigned int i; } c; c.f = f;
  unsigned int r = c.i + 0x7FFFu + ((c.i >> 16) & 1u);
  return (unsigned short)(r >> 16);
}

__device__ __forceinline__ void gload16(const unsigned short* g, unsigned short* l) {
  __builtin_amdgcn_global_load_lds(
      (const __attribute__((address_space(1))) unsigned int*)g,
      (__attribute__((address_space(3))) unsigned int*)l, 16, 0, 0);
}

// ---------------- batched transpose + cast fp32 [R][C] -> bf16 [C][R] (opt. dup K) --------------
template<bool DUPK>
__global__ __launch_bounds__(256)
void transpose_cast(const float* __restrict__ in, unsigned short* __restrict__ out,
                    int R, int C) {
  __shared__ float tile[32][33];
  const size_t batch_off = (size_t)blockIdx.z * R * C;
  const float* bin = in + batch_off;
  unsigned short* bout = out + batch_off * (DUPK ? 2 : 1);
  const int bc = blockIdx.x * 32, br = blockIdx.y * 32;
  const int tx = threadIdx.x & 31, ty = threadIdx.x >> 5;   // 32x8
  const int ostride = DUPK ? 2 * R : R;
  #pragma unroll
  for (int i = 0; i < 32; i += 8)
    tile[ty + i][tx] = bin[(size_t)(br + ty + i) * C + bc + tx];
  __syncthreads();
  #pragma unroll
  for (int i = 0; i < 32; i += 8) {
    const unsigned short v = f2bf(tile[tx][ty + i]);
    bout[(size_t)(bc + ty + i) * ostride + br + tx] = v;
    if (DUPK) bout[(size_t)(bc + ty + i) * ostride + R + br + tx] = v;
  }
}

// ---------------- fp32 x [rows][1024] -> bf16 hi/lo split A2 [rows][2048] ----------------
// A2[:,0:1024] = truncate-to-bf16(x), A2[:,1024:2048] = round-to-bf16(x - hi).
// Same formulas as the previous in-GEMM SPLIT path -> identical numerics.
__global__ __launch_bounds__(256)
void split_cast(const float* __restrict__ x, unsigned short* __restrict__ a2) {
  const size_t idx = ((size_t)blockIdx.x * 256 + threadIdx.x) * 8;
  const size_t r = idx >> 10;
  const int c = (int)(idx & 1023);
  const float4 v0 = *(const float4*)&x[idx];
  const float4 v1 = *(const float4*)&x[idx + 4];
  const float f[8] = {v0.x, v0.y, v0.z, v0.w, v1.x, v1.y, v1.z, v1.w};
  u16x8 hi, lo;
  #pragma unroll
  for (int e = 0; e < 8; e++) {
    union { float f; unsigned u; } cc; cc.f = f[e];
    const unsigned short h = (unsigned short)(cc.u >> 16);
    union { unsigned u; float f; } hb; hb.u = ((unsigned)h) << 16;
    hi[e] = h; lo[e] = f2bf(f[e] - hb.f);
  }
  *(u16x8*)&a2[r * 2048 + c] = hi;
  *(u16x8*)&a2[r * 2048 + 1024 + c] = lo;
}

// ---------------- 256x256 8-phase bf16 GEMM (T1+T2+T3+T4+T5) ----------------
// C[M][N] = A[M][K] @ BT[N][K]^T (+bias). BM=BN=256, BK=64, 8 waves (2M x 4N),
// per-wave 128x64 output. LDS 128 KiB = 2 buf x (A 256x64 + B 256x64) bf16.
// LDS layout: row-major [row][64] with col-XOR swizzle (colbyte ^= (row&7)<<4),
// realized via pre-swizzled GLOBAL source + linear global_load_lds dest (m173).
// Schedule per K-tile t (4 phases): q0 stages A0(t+1), q1 A1(t+1) (buffer freed
// end of t-1); q2 B0(t+2), q3 B1(t+2) (B(t) fully read in q0). vmcnt(4) once per
// tile at q3 => A(t+1),B(t+1) landed, 2 half-tiles (B(t+2)) stay in flight.
#define GPHASE(Q, STG, VMW)                                                        \
  {                                                                                \
    const int ab = arow + (Q) * 2048;                                              \
    bfrag8 a00 = *(const bfrag8*)&lds[b][0][ab + cA0];                             \
    bfrag8 a01 = *(const bfrag8*)&lds[b][0][ab + cA1];                             \
    bfrag8 a10 = *(const bfrag8*)&lds[b][0][ab + 1024 + cA0];                      \
    bfrag8 a11 = *(const bfrag8*)&lds[b][0][ab + 1024 + cA1];                      \
    if ((Q) == 0) {                                                                \
      _Pragma("unroll")                                                            \
      for (int j = 0; j < 4; j++) {                                                \
        bfr[j][0] = *(const bfrag8*)&lds[b][1][brow + j * 1024 + cA0];             \
        bfr[j][1] = *(const bfrag8*)&lds[b][1][brow + j * 1024 + cA1];             \
      }                                                                            \
    }                                                                              \
    STG;                                                                           \
    __builtin_amdgcn_s_barrier();                                                  \
    asm volatile("s_waitcnt lgkmcnt(0)" ::: "memory");                             \
    __builtin_amdgcn_sched_barrier(0);                                             \
    __builtin_amdgcn_s_setprio(1);                                                 \
    _Pragma("unroll")                                                              \
    for (int j = 0; j < 4; j++) {                                                  \
      acc[(Q)*2][j]   = __builtin_amdgcn_mfma_f32_16x16x32_bf16(a00, bfr[j][0], acc[(Q)*2][j], 0, 0, 0);   \
      acc[(Q)*2][j]   = __builtin_amdgcn_mfma_f32_16x16x32_bf16(a01, bfr[j][1], acc[(Q)*2][j], 0, 0, 0);   \
      acc[(Q)*2+1][j] = __builtin_amdgcn_mfma_f32_16x16x32_bf16(a10, bfr[j][0], acc[(Q)*2+1][j], 0, 0, 0); \
      acc[(Q)*2+1][j] = __builtin_amdgcn_mfma_f32_16x16x32_bf16(a11, bfr[j][1], acc[(Q)*2+1][j], 0, 0, 0); \
    }                                                                              \
    __builtin_amdgcn_s_setprio(0);                                                 \
    VMW;                                                                           \
    __builtin_amdgcn_s_barrier();                                                  \
  }

template<bool BIAS, typename OutT>
__global__ __launch_bounds__(512, 2)
void gemm256(const unsigned short* __restrict__ A,
             const unsigned short* __restrict__ BT,
             const float* __restrict__ bias, OutT* __restrict__ C,
             int M, int N, int K) {
  __shared__ alignas(16) unsigned short lds[2][2][256 * 64];
  const int tid = threadIdx.x;
  const int w = tid >> 6, lane = tid & 63;
  const int wm = w >> 2, wn = w & 3;            // 2 x 4 waves
  const int lq = lane >> 4, lr = lane & 15;

  // XCD-aware bijective swizzle (nwg % 8 == 0 for all our launches)
  const int nbx = N >> 8;
  const int cpx = (int)gridDim.x >> 3;
  const int bid = (int)blockIdx.x;
  const int swz = (bid & 7) * cpx + (bid >> 3);
  const int m0 = (swz / nbx) << 8;
  const int n0 = (swz % nbx) << 8;
  const int nkt = K >> 6;

  // staging: thread t -> row (t>>3) of a 64-row segment, col-group pre-swizzled
  const int sr = tid >> 3;
  const int sc = ((tid & 7) ^ (sr & 7)) << 3;
  const unsigned short* gA = A + (size_t)(m0 + sr) * K + sc;
  const unsigned short* gB = BT + (size_t)(n0 + sr) * K + sc;

  // ds_read col offsets with matching XOR swizzle (row&7 == lr&7 for all frags)
  const int swl = (lr & 7) << 3;
  const int cA0 = (lq * 8) ^ swl;
  const int cA1 = (32 + lq * 8) ^ swl;
  const int arow = (wm * 128 + lr) * 64;
  const int brow = (wn * 64 + lr) * 64;

  ffrag4 acc[8][4] = {};
  bfrag8 bfr[4][2];

  auto stage = [&](int bb, int mat, int h, int kt) {
    const unsigned short* g = (mat ? gB : gA) + (size_t)(h * 128) * K + (size_t)kt * 64;
    unsigned short* l = &lds[bb][mat][h * 8192 + tid * 8];
    gload16(g, l);
    gload16(g + (size_t)64 * K, l + 4096);
  };

  // prologue: tile0 A+B -> buf0, tile1 B -> buf1 (12 loads); wait all but last 4
  stage(0, 0, 0, 0); stage(0, 0, 1, 0);
  stage(0, 1, 0, 0); stage(0, 1, 1, 0);
  stage(1, 1, 0, 1); stage(1, 1, 1, 1);
  asm volatile("s_waitcnt vmcnt(4)" ::: "memory");
  __builtin_amdgcn_s_barrier();

  for (int t = 0; t < nkt; ++t) {
    const int b = t & 1;
    const int bn = b ^ 1;
    GPHASE(0, { if (t + 1 < nkt) stage(bn, 0, 0, t + 1); }, {})
    GPHASE(1, { if (t + 1 < nkt) stage(bn, 0, 1, t + 1); }, {})
    GPHASE(2, { if (t + 2 < nkt) stage(b, 1, 0, t + 2); }, {})
    GPHASE(3, { if (t + 2 < nkt) stage(b, 1, 1, t + 2); },
           { if (t < nkt - 2) { asm volatile("s_waitcnt vmcnt(4)" ::: "memory"); }
             else             { asm volatile("s_waitcnt vmcnt(0)" ::: "memory"); } })
  }

  #pragma unroll
  for (int i = 0; i < 8; i++) {
    const int row = m0 + wm * 128 + i * 16 + lq * 4;
    #pragma unroll
    for (int j = 0; j < 4; j++) {
      const int col = n0 + wn * 64 + j * 16 + lr;
      const float bb = BIAS ? bias[col] : 0.f;
      #pragma unroll
      for (int r = 0; r < 4; r++) {
        const float val = acc[i][j][r] + bb;
        if constexpr (sizeof(OutT) == 2) C[(size_t)(row + r) * N + col] = (OutT)f2bf(val);
        else                             C[(size_t)(row + r) * N + col] = (OutT)val;
      }
    }
  }
}

// ---------- Stage A: MFMA k-feature + partial kv/ksum ----------
__global__ __launch_bounds__(256, 1)
void kv_mfma_kernel(const unsigned short* __restrict__ qkv,
                    const unsigned short* __restrict__ projT,  // [H][256f][64d] bf16
                    float* __restrict__ partial) {
  const int c = blockIdx.x, bh = blockIdx.y;
  const int b = bh >> 4, h = bh & 15;
  const int tid = threadIdx.x;
  const int w = tid >> 6, lane = tid & 63;
  const int lq = lane >> 4, lr = lane & 15;
  __shared__ unsigned short pT[256 * 72];   // P^T [f][d], stride 72
  __shared__ unsigned short kp[256 * 72];   // k'  [f][t], stride 72
  __shared__ unsigned short vT[80 * 72];    // V^T [d][t] (+ones row 64), stride 72
  __shared__ float wmax[64][4];
  __shared__ float rmax_s[64];

  #pragma unroll
  for (int e = 0; e < 8; e++) {
    const int job = e * 256 + tid;
    const int f = job >> 3, d0 = (job & 7) * 8;
    const u16x8 v = *(const u16x8*)&projT[(size_t)h * (NF * HD) + f * 64 + d0];
    *(u16x8*)&pT[f * 72 + d0] = v;
  }
  for (int idx = tid; idx < 16 * 72; idx += 256) {
    const int r = idx / 72, cc = idx % 72;
    vT[(64 + r) * 72 + cc] = (r == 0 && cc < 64) ? (unsigned short)0x3F80 : (unsigned short)0;
  }
  __syncthreads();

  ffrag4 acc2[4][5];
  #pragma unroll
  for (int i = 0; i < 4; i++)
    #pragma unroll
    for (int j = 0; j < 5; j++) acc2[i][j] = (ffrag4){0.f, 0.f, 0.f, 0.f};

  const size_t rowbase = (size_t)b * TSEQ + (size_t)c * CH_T;

  for (int tt = 0; tt < CH_T / 64; tt++) {
    const int t0 = tt * 64;
    #pragma unroll
    for (int e = 0; e < 2; e++) {
      const int job = e * 256 + tid;
      const int t = job >> 3, d0 = (job & 7) * 8;
      const u16x8 v = *(const u16x8*)&qkv[(rowbase + t0 + t) * QKV_N + 2048 + h * 64 + d0];
      #pragma unroll
      for (int q = 0; q < 8; q++) vT[(d0 + q) * 72 + t] = v[q];
    }
    ffrag4 accZ[4][4];
    #pragma unroll
    for (int i = 0; i < 4; i++)
      #pragma unroll
      for (int j = 0; j < 4; j++) accZ[i][j] = (ffrag4){0.f, 0.f, 0.f, 0.f};
    #pragma unroll
    for (int kc = 0; kc < 2; kc++) {
      bfrag8 af[4], bfg[4];
      #pragma unroll
      for (int i = 0; i < 4; i++)
        af[i] = *(const bfrag8*)&qkv[(rowbase + t0 + i * 16 + lr) * QKV_N + 1024 + h * 64 + kc * 32 + lq * 8];
      #pragma unroll
      for (int j = 0; j < 4; j++)
        bfg[j] = *(const bfrag8*)&pT[(w * 64 + j * 16 + lr) * 72 + kc * 32 + lq * 8];
      #pragma unroll
      for (int i = 0; i < 4; i++)
        #pragma unroll
        for (int j = 0; j < 4; j++)
          accZ[i][j] = __builtin_amdgcn_mfma_f32_16x16x32_bf16(af[i], bfg[j], accZ[i][j], 0, 0, 0);
    }
    float pmx[4][4];
    #pragma unroll
    for (int i = 0; i < 4; i++)
      #pragma unroll
      for (int r = 0; r < 4; r++) {
        float m = accZ[i][0][r];
        m = fmaxf(m, accZ[i][1][r]); m = fmaxf(m, accZ[i][2][r]); m = fmaxf(m, accZ[i][3][r]);
        pmx[i][r] = m;
      }
    #pragma unroll
    for (int off = 1; off < 16; off <<= 1)
      #pragma unroll
      for (int i = 0; i < 4; i++)
        #pragma unroll
        for (int r = 0; r < 4; r++)
          pmx[i][r] = fmaxf(pmx[i][r], __shfl_xor(pmx[i][r], off, 64));
    if (lr == 0)
      #pragma unroll
      for (int i = 0; i < 4; i++)
        #pragma unroll
        for (int r = 0; r < 4; r++) wmax[i * 16 + lq * 4 + r][w] = pmx[i][r];
    __syncthreads();
    if (tid < 64)
      rmax_s[tid] = fmaxf(fmaxf(wmax[tid][0], wmax[tid][1]), fmaxf(wmax[tid][2], wmax[tid][3]));
    __syncthreads();
    #pragma unroll
    for (int i = 0; i < 4; i++) {
      const float4 rmv = *(const float4*)&rmax_s[i * 16 + lq * 4];
      const float rmarr[4] = {rmv.x, rmv.y, rmv.z, rmv.w};
      #pragma unroll
      for (int j = 0; j < 4; j++) {
        u16x4 pk;
        #pragma unroll
        for (int r = 0; r < 4; r++) pk[r] = f2bf(__expf(accZ[i][j][r] - rmarr[r]));
        *(u16x4*)&kp[(w * 64 + j * 16 + lr) * 72 + i * 16 + lq * 4] = pk;
      }
    }
    __syncthreads();
    #pragma unroll
    for (int kc = 0; kc < 2; kc++) {
      bfrag8 af2[4], bf2[5];
      #pragma unroll
      for (int i = 0; i < 4; i++)
        af2[i] = *(const bfrag8*)&kp[(w * 64 + i * 16 + lr) * 72 + kc * 32 + lq * 8];
      #pragma unroll
      for (int j = 0; j < 5; j++)
        bf2[j] = *(const bfrag8*)&vT[(j * 16 + lr) * 72 + kc * 32 + lq * 8];
      #pragma unroll
      for (int i = 0; i < 4; i++)
        #pragma unroll
        for (int j = 0; j < 5; j++)
          acc2[i][j] = __builtin_amdgcn_mfma_f32_16x16x32_bf16(af2[i], bf2[j], acc2[i][j], 0, 0, 0);
    }
    __syncthreads();
  }
  float* pbase = partial + (size_t)(bh * NCHUNK + c) * NF * KVS;
  #pragma unroll
  for (int i = 0; i < 4; i++)
    #pragma unroll
    for (int j = 0; j < 5; j++) {
      if (j == 4 && lr != 0) continue;
      const int col = j * 16 + lr;
      #pragma unroll
      for (int r = 0; r < 4; r++)
        pbase[(size_t)(w * 64 + i * 16 + lq * 4 + r) * KVS + col] = acc2[i][j][r];
    }
}

// ---------------- reduce kv partials over 8 chunks ----------------
__global__ __launch_bounds__(256)
void kv_reduce_kernel(const float* __restrict__ partial, float* __restrict__ kv) {
  const size_t i = (size_t)blockIdx.x * 256 + threadIdx.x;
  const size_t per_bh = (size_t)NF * KVS;
  const size_t bh = i / per_bh;
  const size_t j = i % per_bh;
  const float* p = partial + bh * NCHUNK * per_bh + j;
  float s = 0.f;
  #pragma unroll
  for (int c = 0; c < NCHUNK; c++) s += p[c * per_bh];
  kv[i] = s;
}

// ---------- Stage B: MFMA q-feature + O = q' @ [KV | ksum] + normalize ----------
__global__ __launch_bounds__(256, 1)
void q_attn_mfma_kernel(const unsigned short* __restrict__ qkv,
                        const unsigned short* __restrict__ projT,
                        const float* __restrict__ kv,
                        unsigned short* __restrict__ attn) {
  const int tb = blockIdx.x, bh = blockIdx.y;
  const int b = bh >> 4, h = bh & 15;
  const int tid = threadIdx.x;
  const int w = tid >> 6, lane = tid & 63;
  const int lq = lane >> 4, lr = lane & 15;
  __shared__ unsigned short pT[256 * 72];
  __shared__ unsigned short qp[64 * 264];
  __shared__ unsigned short kvT[80 * 264];
  __shared__ float wmax[64][4];
  __shared__ float rmax_s[64];

  #pragma unroll
  for (int e = 0; e < 8; e++) {
    const int job = e * 256 + tid;
    const int f = job >> 3, d0 = (job & 7) * 8;
    const u16x8 v = *(const u16x8*)&projT[(size_t)h * (NF * HD) + f * 64 + d0];
    *(u16x8*)&pT[f * 72 + d0] = v;
  }
  {
    const float* kvrow = kv + ((size_t)bh * NF + tid) * KVS;
    #pragma unroll
    for (int d0 = 0; d0 < 64; d0 += 4) {
      const float4 v = *(const float4*)&kvrow[d0];
      kvT[(d0 + 0) * 264 + tid] = f2bf(v.x);
      kvT[(d0 + 1) * 264 + tid] = f2bf(v.y);
      kvT[(d0 + 2) * 264 + tid] = f2bf(v.z);
      kvT[(d0 + 3) * 264 + tid] = f2bf(v.w);
    }
    kvT[64 * 264 + tid] = f2bf(kvrow[64]);
    for (int idx = tid; idx < 15 * 264; idx += 256)
      kvT[65 * 264 + idx] = 0;
  }
  __syncthreads();

  const size_t rowbase = (size_t)b * TSEQ + (size_t)tb * 64;
  ffrag4 accZ[4][4];
  #pragma unroll
  for (int i = 0; i < 4; i++)
    #pragma unroll
    for (int j = 0; j < 4; j++) accZ[i][j] = (ffrag4){0.f, 0.f, 0.f, 0.f};
  #pragma unroll
  for (int kc = 0; kc < 2; kc++) {
    bfrag8 af[4], bfg[4];
    #pragma unroll
    for (int i = 0; i < 4; i++)
      af[i] = *(const bfrag8*)&qkv[(rowbase + i * 16 + lr) * QKV_N + 0 + h * 64 + kc * 32 + lq * 8];
    #pragma unroll
    for (int j = 0; j < 4; j++)
      bfg[j] = *(const bfrag8*)&pT[(w * 64 + j * 16 + lr) * 72 + kc * 32 + lq * 8];
    #pragma unroll
    for (int i = 0; i < 4; i++)
      #pragma unroll
      for (int j = 0; j < 4; j++)
        accZ[i][j] = __builtin_amdgcn_mfma_f32_16x16x32_bf16(af[i], bfg[j], accZ[i][j], 0, 0, 0);
  }
  float pmx[4][4];
  #pragma unroll
  for (int i = 0; i < 4; i++)
    #pragma unroll
    for (int r = 0; r < 4; r++) {
      float m = accZ[i][0][r];
      m = fmaxf(m, accZ[i][1][r]); m = fmaxf(m, accZ[i][2][r]); m = fmaxf(m, accZ[i][3][r]);
      pmx[i][r] = m;
    }
  #pragma unroll
  for (int off = 1; off < 16; off <<= 1)
    #pragma unroll
    for (int i = 0; i < 4; i++)
      #pragma unroll
      for (int r = 0; r < 4; r++)
        pmx[i][r] = fmaxf(pmx[i][r], __shfl_xor(pmx[i][r], off, 64));
  if (lr == 0)
    #pragma unroll
    for (int i = 0; i < 4; i++)
      #pragma unroll
      for (int r = 0; r < 4; r++) wmax[i * 16 + lq * 4 + r][w] = pmx[i][r];
  __syncthreads();
  if (tid < 64)
    rmax_s[tid] = fmaxf(fmaxf(wmax[tid][0], wmax[tid][1]), fmaxf(wmax[tid][2], wmax[tid][3]));
  __syncthreads();
  #pragma unroll
  for (int i = 0; i < 4; i++) {
    const float4 rmv = *(const float4*)&rmax_s[i * 16 + lq * 4];
    const float rmarr[4] = {rmv.x, rmv.y, rmv.z, rmv.w};
    #pragma unroll
    for (int j = 0; j < 4; j++)
      #pragma unroll
      for (int r = 0; r < 4; r++)
        qp[(i * 16 + lq * 4 + r) * 264 + w * 64 + j * 16 + lr] = f2bf(__expf(accZ[i][j][r] - rmarr[r]));
  }
  __syncthreads();
  ffrag4 acc3[5];
  #pragma unroll
  for (int j = 0; j < 5; j++) acc3[j] = (ffrag4){0.f, 0.f, 0.f, 0.f};
  #pragma unroll
  for (int kc = 0; kc < 8; kc++) {
    const bfrag8 afq = *(const bfrag8*)&qp[(w * 16 + lr) * 264 + kc * 32 + lq * 8];
    #pragma unroll
    for (int j = 0; j < 5; j++) {
      const bfrag8 bf3 = *(const bfrag8*)&kvT[(j * 16 + lr) * 264 + kc * 32 + lq * 8];
      acc3[j] = __builtin_amdgcn_mfma_f32_16x16x32_bf16(afq, bf3, acc3[j], 0, 0, 0);
    }
  }
  #pragma unroll
  for (int r = 0; r < 4; r++) {
    const float den = __shfl(acc3[4][r], lane & 48, 64);
    const float z = 1.f / (den + 1e-6f);
    const int t = tb * 64 + w * 16 + lq * 4 + r;
    unsigned short* orow = attn + ((size_t)b * TSEQ + t) * DIM_ + h * 64;
    #pragma unroll
    for (int j = 0; j < 4; j++)
      orow[j * 16 + lr] = f2bf(acc3[j][r] * z);
  }
}

extern "C" void kernel_launch(void* const* d_in, const int* in_sizes, int n_in,
                              void* d_out, int out_size, void* d_ws, size_t ws_size,
                              hipStream_t stream) {
  const float* x     = (const float*)d_in[0];
  const float* w_qkv = (const float*)d_in[1];
  const float* w_out = (const float*)d_in[2];
  const float* b_out = (const float*)d_in[3];
  const float* proj  = (const float*)d_in[4];
  float* out = (float*)d_out;

  // Workspace layout (bytes) — max used 147,324,928 (within prior 147,587,072):
  //   [0,          100663296)  qkv bf16 (16384*3072)
  //   phase 1 (qkv GEMM, per M-half):
  //     [100663296, 134217728)  A2 bf16 (8192*2048)  hi|lo split of x half
  //     [134217728, 146800640)  wqkvT2 bf16 (3072*2048)  [wqkvT | wqkvT]
  //   phase 2 (after gemm1; A2/wqkvT2 dead):
  //     [100663296, 136314880)  partial fp32 (64*8*256*68)   — then:
  //     [100663296, 134217728)  attn bf16 (16384*1024)       (after reduce)
  //     [134217728, 136314880)  woutT bf16 (1024*1024)       (after reduce)
  //     [136314880, 140771328)  kv fp32 (64*256*68)
  //   [146800640, 147324928)  projT bf16 (16*256*64)  — alive throughout
  char* ws = (char*)d_ws;
  unsigned short* qkv    = (unsigned short*)ws;
  unsigned short* a2     = (unsigned short*)(ws + 100663296);
  unsigned short* wqkvT2 = (unsigned short*)(ws + 134217728);
  float*          partial= (float*)(ws + 100663296);
  unsigned short* attn   = (unsigned short*)(ws + 100663296);
  unsigned short* woutT  = (unsigned short*)(ws + 134217728);
  float*          kvbuf  = (float*)(ws + 136314880);
  unsigned short* projT  = (unsigned short*)(ws + 146800640);

  // transposes: w_qkv [1024,3072] -> duplicated [3072,2048]; proj per-head [64,256]->[256,64]
  transpose_cast<true><<<dim3(QKV_N/32, DIM_/32, 1), 256, 0, stream>>>(w_qkv, wqkvT2, DIM_, QKV_N);
  transpose_cast<false><<<dim3(NF/32, HD/32, NH), 256, 0, stream>>>(proj, projT, HD, NF);
  // 1) qkv = x @ w_qkv as plain bf16 K=2048 GEMM over hi|lo split, two M-halves
  for (int hh = 0; hh < 2; ++hh) {
    split_cast<<<4096, 256, 0, stream>>>(x + (size_t)hh * 8192 * DIM_, a2);
    gemm256<false, unsigned short><<<384, 512, 0, stream>>>(
        a2, wqkvT2, nullptr, qkv + (size_t)hh * 8192 * QKV_N, 8192, QKV_N, 2048);
  }
  // 2) MFMA k-feature + partial kv/ksum
  kv_mfma_kernel<<<dim3(NCHUNK, 64), 256, 0, stream>>>(qkv, projT, partial);
  // 3) reduce partials
  kv_reduce_kernel<<<dim3(64*NF*KVS/256), 256, 0, stream>>>(partial, kvbuf);
  // 4) woutT (into region freed by reduce)
  transpose_cast<false><<<dim3(DIM_/32, DIM_/32, 1), 256, 0, stream>>>(w_out, woutT, DIM_, DIM_);
  // 5) MFMA q-feature + q'@kv + normalize -> attn bf16
  q_attn_mfma_kernel<<<dim3(TSEQ/64, 64), 256, 0, stream>>>(qkv, projT, kvbuf, attn);
  // 6) out = attn @ w_out + b_out
  gemm256<true, float><<<256, 512, 0, stream>>>(attn, woutT, b_out, out, TOK, DIM_, DIM_);
}

// Round 2
// 559.216 us; speedup vs baseline: 1.1260x; 1.1260x over previous
//
#include <hip/hip_runtime.h>

#define TOK   16384   // B*T
#define DIM_  1024
#define QKV_N 3072
#define NH    16
#define HD    64
#define NF    256
#define TSEQ  4096
#define NCHUNK 8
#define CH_T  512     // TSEQ/NCHUNK
#define KVS   68      // kv row stride (64 d + 1 ksum + pad)

typedef __attribute__((ext_vector_type(8))) short  bfrag8;   // 8 bf16 (4 VGPRs)
typedef __attribute__((ext_vector_type(4))) float  ffrag4;   // 4 fp32 acc
typedef __attribute__((ext_vector_type(8))) unsigned short u16x8;
typedef __attribute__((ext_vector_type(4))) unsigned short u16x4;

__device__ __forceinline__ float bf2f(unsigned short u) {
  union { unsigned int i; float f; } c; c.i = ((unsigned int)u) << 16; return c.f;
}
__device__ __forceinline__ unsigned short f2bf(float f) {
  union { float f; unsigned int i; } c; c.f = f;
  unsigned int r = c.i + 0x7FFFu + ((c.i >> 16) & 1u);
  return (unsigned short)(r >> 16);
}

__device__ __forceinline__ void gload16(const unsigned short* g, unsigned short* l) {
  __builtin_amdgcn_global_load_lds(
      (const __attribute__((address_space(1))) unsigned int*)g,
      (__attribute__((address_space(3))) unsigned int*)l, 16, 0, 0);
}

// ---------------- batched transpose + cast fp32 [R][C] -> bf16 [C][R] (opt. dup K) --------------
template<bool DUPK>
__global__ __launch_bounds__(256)
void transpose_cast(const float* __restrict__ in, unsigned short* __restrict__ out,
                    int R, int C) {
  __shared__ float tile[32][33];
  const size_t batch_off = (size_t)blockIdx.z * R * C;
  const float* bin = in + batch_off;
  unsigned short* bout = out + batch_off * (DUPK ? 2 : 1);
  const int bc = blockIdx.x * 32, br = blockIdx.y * 32;
  const int tx = threadIdx.x & 31, ty = threadIdx.x >> 5;   // 32x8
  const int ostride = DUPK ? 2 * R : R;
  #pragma unroll
  for (int i = 0; i < 32; i += 8)
    tile[ty + i][tx] = bin[(size_t)(br + ty + i) * C + bc + tx];
  __syncthreads();
  #pragma unroll
  for (int i = 0; i < 32; i += 8) {
    const unsigned short v = f2bf(tile[tx][ty + i]);
    bout[(size_t)(bc + ty + i) * ostride + br + tx] = v;
    if (DUPK) bout[(size_t)(bc + ty + i) * ostride + R + br + tx] = v;
  }
}

// ---------------- fp32 x [rows][1024] -> bf16 hi/lo split A2 [rows][2048] ----------------
// A2[:,0:1024] = truncate-to-bf16(x), A2[:,1024:2048] = round-to-bf16(x - hi).
__global__ __launch_bounds__(256)
void split_cast(const float* __restrict__ x, unsigned short* __restrict__ a2) {
  const size_t idx = ((size_t)blockIdx.x * 256 + threadIdx.x) * 8;
  const size_t r = idx >> 10;
  const int c = (int)(idx & 1023);
  const float4 v0 = *(const float4*)&x[idx];
  const float4 v1 = *(const float4*)&x[idx + 4];
  const float f[8] = {v0.x, v0.y, v0.z, v0.w, v1.x, v1.y, v1.z, v1.w};
  u16x8 hi, lo;
  #pragma unroll
  for (int e = 0; e < 8; e++) {
    union { float f; unsigned u; } cc; cc.f = f[e];
    const unsigned short h = (unsigned short)(cc.u >> 16);
    union { unsigned u; float f; } hb; hb.u = ((unsigned)h) << 16;
    hi[e] = h; lo[e] = f2bf(f[e] - hb.f);
  }
  *(u16x8*)&a2[r * 2048 + c] = hi;
  *(u16x8*)&a2[r * 2048 + 1024 + c] = lo;
}

// ---------------- 256x256 8-phase bf16 GEMM (T1+T2+T3+T4+T5) ----------------
#define GPHASE(Q, STG, VMW)                                                        \
  {                                                                                \
    const int ab = arow + (Q) * 2048;                                              \
    bfrag8 a00 = *(const bfrag8*)&lds[b][0][ab + cA0];                             \
    bfrag8 a01 = *(const bfrag8*)&lds[b][0][ab + cA1];                             \
    bfrag8 a10 = *(const bfrag8*)&lds[b][0][ab + 1024 + cA0];                      \
    bfrag8 a11 = *(const bfrag8*)&lds[b][0][ab + 1024 + cA1];                      \
    if ((Q) == 0) {                                                                \
      _Pragma("unroll")                                                            \
      for (int j = 0; j < 4; j++) {                                                \
        bfr[j][0] = *(const bfrag8*)&lds[b][1][brow + j * 1024 + cA0];             \
        bfr[j][1] = *(const bfrag8*)&lds[b][1][brow + j * 1024 + cA1];             \
      }                                                                            \
    }                                                                              \
    STG;                                                                           \
    __builtin_amdgcn_s_barrier();                                                  \
    asm volatile("s_waitcnt lgkmcnt(0)" ::: "memory");                             \
    __builtin_amdgcn_sched_barrier(0);                                             \
    __builtin_amdgcn_s_setprio(1);                                                 \
    _Pragma("unroll")                                                              \
    for (int j = 0; j < 4; j++) {                                                  \
      acc[(Q)*2][j]   = __builtin_amdgcn_mfma_f32_16x16x32_bf16(a00, bfr[j][0], acc[(Q)*2][j], 0, 0, 0);   \
      acc[(Q)*2][j]   = __builtin_amdgcn_mfma_f32_16x16x32_bf16(a01, bfr[j][1], acc[(Q)*2][j], 0, 0, 0);   \
      acc[(Q)*2+1][j] = __builtin_amdgcn_mfma_f32_16x16x32_bf16(a10, bfr[j][0], acc[(Q)*2+1][j], 0, 0, 0); \
      acc[(Q)*2+1][j] = __builtin_amdgcn_mfma_f32_16x16x32_bf16(a11, bfr[j][1], acc[(Q)*2+1][j], 0, 0, 0); \
    }                                                                              \
    __builtin_amdgcn_s_setprio(0);                                                 \
    VMW;                                                                           \
    __builtin_amdgcn_s_barrier();                                                  \
  }

template<bool BIAS, typename OutT>
__global__ __launch_bounds__(512, 2)
void gemm256(const unsigned short* __restrict__ A,
             const unsigned short* __restrict__ BT,
             const float* __restrict__ bias, OutT* __restrict__ C,
               int M, int N, int K) {
  __shared__ alignas(16) unsigned short lds[2][2][256 * 64];
  const int tid = threadIdx.x;
  const int w = tid >> 6, lane = tid & 63;
  const int wm = w >> 2, wn = w & 3;            // 2 x 4 waves
  const int lq = lane >> 4, lr = lane & 15;

  const int nbx = N >> 8;
  const int cpx = (int)gridDim.x >> 3;
  const int bid = (int)blockIdx.x;
  const int swz = (bid & 7) * cpx + (bid >> 3);
  const int m0 = (swz / nbx) << 8;
  const int n0 = (swz % nbx) << 8;
  const int nkt = K >> 6;

  const int sr = tid >> 3;
  const int sc = ((tid & 7) ^ (sr & 7)) << 3;
  const unsigned short* gA = A + (size_t)(m0 + sr) * K + sc;
  const unsigned short* gB = BT + (size_t)(n0 + sr) * K + sc;

  const int swl = (lr & 7) << 3;
  const int cA0 = (lq * 8) ^ swl;
  const int cA1 = (32 + lq * 8) ^ swl;
  const int arow = (wm * 128 + lr) * 64;
  const int brow = (wn * 64 + lr) * 64;

  ffrag4 acc[8][4] = {};
  bfrag8 bfr[4][2];

  auto stage = [&](int bb, int mat, int h, int kt) {
    const unsigned short* g = (mat ? gB : gA) + (size_t)(h * 128) * K + (size_t)kt * 64;
    unsigned short* l = &lds[bb][mat][h * 8192 + tid * 8];
    gload16(g, l);
    gload16(g + (size_t)64 * K, l + 4096);
  };

  stage(0, 0, 0, 0); stage(0, 0, 1, 0);
  stage(0, 1, 0, 0); stage(0, 1, 1, 0);
  stage(1, 1, 0, 1); stage(1, 1, 1, 1);
  asm volatile("s_waitcnt vmcnt(4)" ::: "memory");
  __builtin_amdgcn_s_barrier();

  for (int t = 0; t < nkt; ++t) {
    const int b = t & 1;
    const int bn = b ^ 1;
    GPHASE(0, { if (t + 1 < nkt) stage(bn, 0, 0, t + 1); }, {})
    GPHASE(1, { if (t + 1 < nkt) stage(bn, 0, 1, t + 1); }, {})
    GPHASE(2, { if (t + 2 < nkt) stage(b, 1, 0, t + 2); }, {})
    GPHASE(3, { if (t + 2 < nkt) stage(b, 1, 1, t + 2); },
           { if (t < nkt - 2) { asm volatile("s_waitcnt vmcnt(4)" ::: "memory"); }
             else             { asm volatile("s_waitcnt vmcnt(0)" ::: "memory"); } })
  }

  #pragma unroll
  for (int i = 0; i < 8; i++) {
    const int row = m0 + wm * 128 + i * 16 + lq * 4;
    #pragma unroll
    for (int j = 0; j < 4; j++) {
      const int col = n0 + wn * 64 + j * 16 + lr;
      const float bb = BIAS ? bias[col] : 0.f;
      #pragma unroll
      for (int r = 0; r < 4; r++) {
        const float val = acc[i][j][r] + bb;
        if constexpr (sizeof(OutT) == 2) C[(size_t)(row + r) * N + col] = (OutT)f2bf(val);
        else                             C[(size_t)(row + r) * N + col] = (OutT)val;
      }
    }
  }
}

// ---------- Stage A: MFMA k-feature + partial kv/ksum ----------
__global__ __launch_bounds__(256, 1)
void kv_mfma_kernel(const unsigned short* __restrict__ qkv,
                    const unsigned short* __restrict__ projT,  // [H][256f][64d] bf16
                    float* __restrict__ partial) {
  const int c = blockIdx.x, bh = blockIdx.y;
  const int b = bh >> 4, h = bh & 15;
  const int tid = threadIdx.x;
  const int w = tid >> 6, lane = tid & 63;
  const int lq = lane >> 4, lr = lane & 15;
  __shared__ unsigned short pT[256 * 72];   // P^T [f][d], stride 72
  __shared__ unsigned short kp[256 * 72];   // k'  [f][t], stride 72
  __shared__ unsigned short vT[80 * 72];    // V^T [d][t] (+ones row 64), stride 72
  __shared__ float wmax[64][4];
  __shared__ float rmax_s[64];

  #pragma unroll
  for (int e = 0; e < 8; e++) {
    const int job = e * 256 + tid;
    const int f = job >> 3, d0 = (job & 7) * 8;
    const u16x8 v = *(const u16x8*)&projT[(size_t)h * (NF * HD) + f * 64 + d0];
    *(u16x8*)&pT[f * 72 + d0] = v;
  }
  for (int idx = tid; idx < 16 * 72; idx += 256) {
    const int r = idx / 72, cc = idx % 72;
    vT[(64 + r) * 72 + cc] = (r == 0 && cc < 64) ? (unsigned short)0x3F80 : (unsigned short)0;
  }
  __syncthreads();

  ffrag4 acc2[4][5];
  #pragma unroll
  for (int i = 0; i < 4; i++)
    #pragma unroll
    for (int j = 0; j < 5; j++) acc2[i][j] = (ffrag4){0.f, 0.f, 0.f, 0.f};

  const size_t rowbase = (size_t)b * TSEQ + (size_t)c * CH_T;

  for (int tt = 0; tt < CH_T / 64; tt++) {
    const int t0 = tt * 64;
    #pragma unroll
    for (int e = 0; e < 2; e++) {
      const int job = e * 256 + tid;
      const int t = job >> 3, d0 = (job & 7) * 8;
      const u16x8 v = *(const u16x8*)&qkv[(rowbase + t0 + t) * QKV_N + 2048 + h * 64 + d0];
      #pragma unroll
      for (int q = 0; q < 8; q++) vT[(d0 + q) * 72 + t] = v[q];
    }
    ffrag4 accZ[4][4];
    #pragma unroll
    for (int i = 0; i < 4; i++)
      #pragma unroll
      for (int j = 0; j < 4; j++) accZ[i][j] = (ffrag4){0.f, 0.f, 0.f, 0.f};
    #pragma unroll
    for (int kc = 0; kc < 2; kc++) {
      bfrag8 af[4], bfg[4];
      #pragma unroll
      for (int i = 0; i < 4; i++)
        af[i] = *(const bfrag8*)&qkv[(rowbase + t0 + i * 16 + lr) * QKV_N + 1024 + h * 64 + kc * 32 + lq * 8];
      #pragma unroll
      for (int j = 0; j < 4; j++)
        bfg[j] = *(const bfrag8*)&pT[(w * 64 + j * 16 + lr) * 72 + kc * 32 + lq * 8];
      #pragma unroll
      for (int i = 0; i < 4; i++)
        #pragma unroll
        for (int j = 0; j < 4; j++)
          accZ[i][j] = __builtin_amdgcn_mfma_f32_16x16x32_bf16(af[i], bfg[j], accZ[i][j], 0, 0, 0);
    }
    float pmx[4][4];
    #pragma unroll
    for (int i = 0; i < 4; i++)
      #pragma unroll
      for (int r = 0; r < 4; r++) {
        float m = accZ[i][0][r];
        m = fmaxf(m, accZ[i][1][r]); m = fmaxf(m, accZ[i][2][r]); m = fmaxf(m, accZ[i][3][r]);
        pmx[i][r] = m;
      }
    #pragma unroll
    for (int off = 1; off < 16; off <<= 1)
      #pragma unroll
      for (int i = 0; i < 4; i++)
        #pragma unroll
        for (int r = 0; r < 4; r++)
          pmx[i][r] = fmaxf(pmx[i][r], __shfl_xor(pmx[i][r], off, 64));
    if (lr == 0)
      #pragma unroll
      for (int i = 0; i < 4; i++)
        #pragma unroll
        for (int r = 0; r < 4; r++) wmax[i * 16 + lq * 4 + r][w] = pmx[i][r];
    __syncthreads();
    if (tid < 64)
      rmax_s[tid] = fmaxf(fmaxf(wmax[tid][0], wmax[tid][1]), fmaxf(wmax[tid][2], wmax[tid][3]));
    __syncthreads();
    #pragma unroll
    for (int i = 0; i < 4; i++) {
      const float4 rmv = *(const float4*)&rmax_s[i * 16 + lq * 4];
      const float rmarr[4] = {rmv.x, rmv.y, rmv.z, rmv.w};
      #pragma unroll
      for (int j = 0; j < 4; j++) {
        u16x4 pk;
        #pragma unroll
        for (int r = 0; r < 4; r++) pk[r] = f2bf(__expf(accZ[i][j][r] - rmarr[r]));
        *(u16x4*)&kp[(w * 64 + j * 16 + lr) * 72 + i * 16 + lq * 4] = pk;
      }
    }
    __syncthreads();
    #pragma unroll
    for (int kc = 0; kc < 2; kc++) {
      bfrag8 af2[4], bf2[5];
      #pragma unroll
      for (int i = 0; i < 4; i++)
        af2[i] = *(const bfrag8*)&kp[(w * 64 + i * 16 + lr) * 72 + kc * 32 + lq * 8];
      #pragma unroll
      for (int j = 0; j < 5; j++)
        bf2[j] = *(const bfrag8*)&vT[(j * 16 + lr) * 72 + kc * 32 + lq * 8];
      #pragma unroll
      for (int i = 0; i < 4; i++)
        #pragma unroll
        for (int j = 0; j < 5; j++)
          acc2[i][j] = __builtin_amdgcn_mfma_f32_16x16x32_bf16(af2[i], bf2[j], acc2[i][j], 0, 0, 0);
    }
    __syncthreads();
  }
  float* pbase = partial + (size_t)(bh * NCHUNK + c) * NF * KVS;
  #pragma unroll
  for (int i = 0; i < 4; i++)
    #pragma unroll
    for (int j = 0; j < 5; j++) {
      if (j == 4 && lr != 0) continue;
      const int col = j * 16 + lr;
      #pragma unroll
      for (int r = 0; r < 4; r++)
        pbase[(size_t)(w * 64 + i * 16 + lq * 4 + r) * KVS + col] = acc2[i][j][r];
    }
}

// ---------------- reduce kv partials over 8 chunks ----------------
__global__ __launch_bounds__(256)
void kv_reduce_kernel(const float* __restrict__ partial, float* __restrict__ kv) {
  const size_t i = (size_t)blockIdx.x * 256 + threadIdx.x;
  const size_t per_bh = (size_t)NF * KVS;
  const size_t bh = i / per_bh;
  const size_t j = i % per_bh;
  const float* p = partial + bh * NCHUNK * per_bh + j;
  float s = 0.f;
  #pragma unroll
  for (int c = 0; c < NCHUNK; c++) s += p[c * per_bh];
  kv[i] = s;
}

// ---------- Stage B: MFMA q-feature + O = q' @ [KV | ksum] + normalize ----------
// v2: grid (NCHUNK, B*H) — each block owns 512 tokens (8 x 64-token subtiles).
// KV^T staged in LDS ONCE per block; P fragments hoisted to registers (no pT LDS).
// LDS 77.3 KB -> 2 blocks/CU (8 waves/CU) for cross-block latency hiding.
__global__ __launch_bounds__(256, 2)
void q_attn_mfma_kernel(const unsigned short* __restrict__ qkv,
                        const unsigned short* __restrict__ projT,
                        const float* __restrict__ kv,
                        unsigned short* __restrict__ attn) {
  const int c = blockIdx.x, bh = blockIdx.y;
  const int b = bh >> 4, h = bh & 15;
  const int tid = threadIdx.x;
  const int w = tid >> 6, lane = tid & 63;
  const int lq = lane >> 4, lr = lane & 15;
  __shared__ unsigned short qp[64 * 264];    // q' [t][f], stride 264
  __shared__ unsigned short kvT[80 * 264];   // KV^T [d][f] (+ksum row 64)
  __shared__ float wmax[64][4];
  __shared__ float rmax_s[64];

  // stage KV^T bf16 once per block (thread tid owns kv row tid = feature f)
  {
    const float* kvrow = kv + ((size_t)bh * NF + tid) * KVS;
    #pragma unroll
    for (int d0 = 0; d0 < 64; d0 += 4) {
      const float4 v = *(const float4*)&kvrow[d0];
      kvT[(d0 + 0) * 264 + tid] = f2bf(v.x);
      kvT[(d0 + 1) * 264 + tid] = f2bf(v.y);
      kvT[(d0 + 2) * 264 + tid] = f2bf(v.z);
      kvT[(d0 + 3) * 264 + tid] = f2bf(v.w);
    }
    kvT[64 * 264 + tid] = f2bf(kvrow[64]);
    for (int idx = tid; idx < 15 * 264; idx += 256)
      kvT[65 * 264 + idx] = 0;
  }
  // hoist P fragments: constant per block, reused by all 8 subtiles
  const unsigned short* pTg = projT + (size_t)h * (NF * HD);
  bfrag8 bfg[2][4];
  #pragma unroll
  for (int kc = 0; kc < 2; kc++)
    #pragma unroll
    for (int j = 0; j < 4; j++)
      bfg[kc][j] = *(const bfrag8*)&pTg[(size_t)(w * 64 + j * 16 + lr) * 64 + kc * 32 + lq * 8];
  __syncthreads();

  for (int tt = 0; tt < CH_T / 64; tt++) {
    const size_t rowbase = (size_t)b * TSEQ + (size_t)c * CH_T + (size_t)tt * 64;
    // Z = Q @ P (A fragments direct from global, B from registers)
    ffrag4 accZ[4][4];
    #pragma unroll
    for (int i = 0; i < 4; i++)
      #pragma unroll
      for (int j = 0; j < 4; j++) accZ[i][j] = (ffrag4){0.f, 0.f, 0.f, 0.f};
    #pragma unroll
    for (int kc = 0; kc < 2; kc++) {
      bfrag8 af[4];
      #pragma unroll
      for (int i = 0; i < 4; i++)
        af[i] = *(const bfrag8*)&qkv[(rowbase + i * 16 + lr) * QKV_N + 0 + h * 64 + kc * 32 + lq * 8];
      #pragma unroll
      for (int i = 0; i < 4; i++)
        #pragma unroll
        for (int j = 0; j < 4; j++)
          accZ[i][j] = __builtin_amdgcn_mfma_f32_16x16x32_bf16(af[i], bfg[kc][j], accZ[i][j], 0, 0, 0);
    }
    // rowmax over f
    float pmx[4][4];
    #pragma unroll
    for (int i = 0; i < 4; i++)
      #pragma unroll
      for (int r = 0; r < 4; r++) {
        float m = accZ[i][0][r];
        m = fmaxf(m, accZ[i][1][r]); m = fmaxf(m, accZ[i][2][r]); m = fmaxf(m, accZ[i][3][r]);
        pmx[i][r] = m;
      }
    #pragma unroll
    for (int off = 1; off < 16; off <<= 1)
      #pragma unroll
      for (int i = 0; i < 4; i++)
        #pragma unroll
        for (int r = 0; r < 4; r++)
          pmx[i][r] = fmaxf(pmx[i][r], __shfl_xor(pmx[i][r], off, 64));
    if (lr == 0)
      #pragma unroll
      for (int i = 0; i < 4; i++)
        #pragma unroll
        for (int r = 0; r < 4; r++) wmax[i * 16 + lq * 4 + r][w] = pmx[i][r];
    __syncthreads();
    if (tid < 64)
      rmax_s[tid] = fmaxf(fmaxf(wmax[tid][0], wmax[tid][1]), fmaxf(wmax[tid][2], wmax[tid][3]));
    __syncthreads();
    // exp -> qp[t][f]
    #pragma unroll
    for (int i = 0; i < 4; i++) {
      const float4 rmv = *(const float4*)&rmax_s[i * 16 + lq * 4];
      const float rmarr[4] = {rmv.x, rmv.y, rmv.z, rmv.w};
      #pragma unroll
      for (int j = 0; j < 4; j++)
        #pragma unroll
        for (int r = 0; r < 4; r++)
          qp[(i * 16 + lq * 4 + r) * 264 + w * 64 + j * 16 + lr] = f2bf(__expf(accZ[i][j][r] - rmarr[r]));
    }
    __syncthreads();
    // O = q' @ [KV | ksum]; wave w owns 16 t-rows
    ffrag4 acc3[5];
    #pragma unroll
    for (int j = 0; j < 5; j++) acc3[j] = (ffrag4){0.f, 0.f, 0.f, 0.f};
    #pragma unroll
    for (int kc = 0; kc < 8; kc++) {
      const bfrag8 afq = *(const bfrag8*)&qp[(w * 16 + lr) * 264 + kc * 32 + lq * 8];
      #pragma unroll
      for (int j = 0; j < 5; j++) {
        const bfrag8 bf3 = *(const bfrag8*)&kvT[(j * 16 + lr) * 264 + kc * 32 + lq * 8];
        acc3[j] = __builtin_amdgcn_mfma_f32_16x16x32_bf16(afq, bf3, acc3[j], 0, 0, 0);
      }
    }
    // epilogue: den = col 64, broadcast, normalize, store
    #pragma unroll
    for (int r = 0; r < 4; r++) {
      const float den = __shfl(acc3[4][r], lane & 48, 64);
      const float z = 1.f / (den + 1e-6f);
      const int t = c * CH_T + tt * 64 + w * 16 + lq * 4 + r;
      unsigned short* orow = attn + ((size_t)b * TSEQ + t) * DIM_ + h * 64;
      #pragma unroll
      for (int j = 0; j < 4; j++)
        orow[j * 16 + lr] = f2bf(acc3[j][r] * z);
    }
    __syncthreads();   // protect qp/wmax before next subtile overwrites
  }
}

extern "C" void kernel_launch(void* const* d_in, const int* in_sizes, int n_in,
                              void* d_out, int out_size, void* d_ws, size_t ws_size,
                              hipStream_t stream) {
  const float* x     = (const float*)d_in[0];
  const float* w_qkv = (const float*)d_in[1];
  const float* w_out = (const float*)d_in[2];
  const float* b_out = (const float*)d_in[3];
  const float* proj  = (const float*)d_in[4];
  float* out = (float*)d_out;

  // Workspace layout (bytes) — max used 147,324,928:
  //   [0,          100663296)  qkv bf16 (16384*3072)
  //   phase 1 (qkv GEMM, per M-half):
  //     [100663296, 134217728)  A2 bf16 (8192*2048)  hi|lo split of x half
  //     [134217728, 146800640)  wqkvT2 bf16 (3072*2048)  [wqkvT | wqkvT]
  //   phase 2 (after gemm1; A2/wqkvT2 dead):
  //     [100663296, 136314880)  partial fp32 (64*8*256*68)   — then:
  //     [100663296, 134217728)  attn bf16 (16384*1024)       (after reduce)
  //     [134217728, 136314880)  woutT bf16 (1024*1024)       (after reduce)
  //     [136314880, 140771328)  kv fp32 (64*256*68)
  //   [146800640, 147324928)  projT bf16 (16*256*64)  — alive throughout
  char* ws = (char*)d_ws;
  unsigned short* qkv    = (unsigned short*)ws;
  unsigned short* a2     = (unsigned short*)(ws + 100663296);
  unsigned short* wqkvT2 = (unsigned short*)(ws + 134217728);
  float*          partial= (float*)(ws + 100663296);
  unsigned short* attn   = (unsigned short*)(ws + 100663296);
  unsigned short* woutT  = (unsigned short*)(ws + 134217728);
  float*          kvbuf  = (float*)(ws + 136314880);
  unsigned short* projT  = (unsigned short*)(ws + 146800640);

  transpose_cast<true><<<dim3(QKV_N/32, DIM_/32, 1), 256, 0, stream>>>(w_qkv, wqkvT2, DIM_, QKV_N);
  transpose_cast<false><<<dim3(NF/32, HD/32, NH), 256, 0, stream>>>(proj, projT, HD, NF);
  // 1) qkv = x @ w_qkv as plain bf16 K=2048 GEMM over hi|lo split, two M-halves
  for (int hh = 0; hh < 2; ++hh) {
    split_cast<<<4096, 256, 0, stream>>>(x + (size_t)hh * 8192 * DIM_, a2);
    gemm256<false, unsigned short><<<384, 512, 0, stream>>>(
        a2, wqkvT2, nullptr, qkv + (size_t)hh * 8192 * QKV_N, 8192, QKV_N, 2048);
  }
  // 2) MFMA k-feature + partial kv/ksum
  kv_mfma_kernel<<<dim3(NCHUNK, 64), 256, 0, stream>>>(qkv, projT, partial);
  // 3) reduce partials
  kv_reduce_kernel<<<dim3(64*NF*KVS/256), 256, 0, stream>>>(partial, kvbuf);
  // 4) woutT (into region freed by reduce)
  transpose_cast<false><<<dim3(DIM_/32, DIM_/32, 1), 256, 0, stream>>>(w_out, woutT, DIM_, DIM_);
  // 5) MFMA q-feature + q'@kv + normalize -> attn bf16 (v2: chunked, 2 blocks/CU)
  q_attn_mfma_kernel<<<dim3(NCHUNK, 64), 256, 0, stream>>>(qkv, projT, kvbuf, attn);
  // 6) out = attn @ w_out + b_out
  gemm256<true, float><<<256, 512, 0, stream>>>(attn, woutT, b_out, out, TOK, DIM_, DIM_);
}

// Round 3
// 500.296 us; speedup vs baseline: 1.2586x; 1.1178x over previous
//
#include <hip/hip_runtime.h>

#define TOK   16384   // B*T
#define DIM_  1024
#define QKV_N 3072
#define NH    16
#define HD    64
#define NF    256
#define TSEQ  4096
#define NCHUNK 8
#define CH_T  512     // TSEQ/NCHUNK
#define KVS   68      // kv row stride (64 d + 1 ksum + pad)

typedef __attribute__((ext_vector_type(8))) short  bfrag8;   // 8 bf16 (4 VGPRs)
typedef __attribute__((ext_vector_type(4))) float  ffrag4;   // 4 fp32 acc
typedef __attribute__((ext_vector_type(8))) unsigned short u16x8;
typedef __attribute__((ext_vector_type(4))) unsigned short u16x4;

__device__ __forceinline__ float bf2f(unsigned short u) {
  union { unsigned int i; float f; } c; c.i = ((unsigned int)u) << 16; return c.f;
}
__device__ __forceinline__ unsigned short f2bf(float f) {
  union { float f; unsigned int i; } c; c.f = f;
  unsigned int r = c.i + 0x7FFFu + ((c.i >> 16) & 1u);
  return (unsigned short)(r >> 16);
}

__device__ __forceinline__ void gload16(const unsigned short* g, unsigned short* l) {
  __builtin_amdgcn_global_load_lds(
      (const __attribute__((address_space(1))) unsigned int*)g,
      (__attribute__((address_space(3))) unsigned int*)l, 16, 0, 0);
}

// ---------------- batched transpose + cast fp32 [R][C] -> bf16 [C][R] ----------------
__global__ __launch_bounds__(256)
void transpose_cast(const float* __restrict__ in, unsigned short* __restrict__ out,
                    int R, int C) {
  __shared__ float tile[32][33];
  const size_t batch_off = (size_t)blockIdx.z * R * C;
  const float* bin = in + batch_off;
  unsigned short* bout = out + batch_off;
  const int bc = blockIdx.x * 32, br = blockIdx.y * 32;
  const int tx = threadIdx.x & 31, ty = threadIdx.x >> 5;   // 32x8
  #pragma unroll
  for (int i = 0; i < 32; i += 8)
    tile[ty + i][tx] = bin[(size_t)(br + ty + i) * C + bc + tx];
  __syncthreads();
  #pragma unroll
  for (int i = 0; i < 32; i += 8)
    bout[(size_t)(bc + ty + i) * R + br + tx] = f2bf(tile[tx][ty + i]);
}

// ---------------- fp32 x [rows][1024] -> bf16 hi/lo split A2 [rows][2048] ----------------
// A2[:,0:1024] = truncate-to-bf16(x), A2[:,1024:2048] = round-to-bf16(x - hi).
__global__ __launch_bounds__(256)
void split_cast(const float* __restrict__ x, unsigned short* __restrict__ a2) {
  const size_t idx = ((size_t)blockIdx.x * 256 + threadIdx.x) * 8;
  const size_t r = idx >> 10;
  const int c = (int)(idx & 1023);
  const float4 v0 = *(const float4*)&x[idx];
  const float4 v1 = *(const float4*)&x[idx + 4];
  const float f[8] = {v0.x, v0.y, v0.z, v0.w, v1.x, v1.y, v1.z, v1.w};
  u16x8 hi, lo;
  #pragma unroll
  for (int e = 0; e < 8; e++) {
    union { float f; unsigned u; } cc; cc.f = f[e];
    const unsigned short h = (unsigned short)(cc.u >> 16);
    union { unsigned u; float f; } hb; hb.u = ((unsigned)h) << 16;
    hi[e] = h; lo[e] = f2bf(f[e] - hb.f);
  }
  *(u16x8*)&a2[r * 2048 + c] = hi;
  *(u16x8*)&a2[r * 2048 + 1024 + c] = lo;
}

// ---------------- 256x256 8-phase bf16 GEMM (T1+T2+T3+T4+T5) ----------------
// C[M][N] = A[M][K] @ BT[N][KB]^T (+bias), with B K-tiles wrapped mod KB/64 —
// lets K=2048 hi|lo A-planes multiply an UN-duplicated B (hi@W + lo@W).
#define GPHASE(Q, STG, VMW)                                                        \
  {                                                                                \
    const int ab = arow + (Q) * 2048;                                              \
    bfrag8 a00 = *(const bfrag8*)&lds[b][0][ab + cA0];                             \
    bfrag8 a01 = *(const bfrag8*)&lds[b][0][ab + cA1];                             \
    bfrag8 a10 = *(const bfrag8*)&lds[b][0][ab + 1024 + cA0];                      \
    bfrag8 a11 = *(const bfrag8*)&lds[b][0][ab + 1024 + cA1];                      \
    if ((Q) == 0) {                                                                \
      _Pragma("unroll")                                                            \
      for (int j = 0; j < 4; j++) {                                                \
        bfr[j][0] = *(const bfrag8*)&lds[b][1][brow + j * 1024 + cA0];             \
        bfr[j][1] = *(const bfrag8*)&lds[b][1][brow + j * 1024 + cA1];             \
      }                                                                            \
    }                                                                              \
    STG;                                                                           \
    __builtin_amdgcn_s_barrier();                                                  \
    asm volatile("s_waitcnt lgkmcnt(0)" ::: "memory");                             \
    __builtin_amdgcn_sched_barrier(0);                                             \
    __builtin_amdgcn_s_setprio(1);                                                 \
    _Pragma("unroll")                                                              \
    for (int j = 0; j < 4; j++) {                                                  \
      acc[(Q)*2][j]   = __builtin_amdgcn_mfma_f32_16x16x32_bf16(a00, bfr[j][0], acc[(Q)*2][j], 0, 0, 0);   \
      acc[(Q)*2][j]   = __builtin_amdgcn_mfma_f32_16x16x32_bf16(a01, bfr[j][1], acc[(Q)*2][j], 0, 0, 0);   \
      acc[(Q)*2+1][j] = __builtin_amdgcn_mfma_f32_16x16x32_bf16(a10, bfr[j][0], acc[(Q)*2+1][j], 0, 0, 0); \
      acc[(Q)*2+1][j] = __builtin_amdgcn_mfma_f32_16x16x32_bf16(a11, bfr[j][1], acc[(Q)*2+1][j], 0, 0, 0); \
    }                                                                              \
    __builtin_amdgcn_s_setprio(0);                                                 \
    VMW;                                                                           \
    __builtin_amdgcn_s_barrier();                                                  \
  }

template<bool BIAS, typename OutT>
__global__ __launch_bounds__(512, 2)
void gemm256(const unsigned short* __restrict__ A,
             const unsigned short* __restrict__ BT,
             const float* __restrict__ bias, OutT* __restrict__ C,
             int M, int N, int K, int KB) {
  __shared__ alignas(16) unsigned short lds[2][2][256 * 64];
  const int tid = threadIdx.x;
  const int w = tid >> 6, lane = tid & 63;
  const int wm = w >> 2, wn = w & 3;            // 2 x 4 waves
  const int lq = lane >> 4, lr = lane & 15;

  const int nbx = N >> 8;
  const int cpx = (int)gridDim.x >> 3;
  const int bid = (int)blockIdx.x;
  const int swz = (bid & 7) * cpx + (bid >> 3);
  const int m0 = (swz / nbx) << 8;
  const int n0 = (swz % nbx) << 8;
  const int nkt = K >> 6;
  const int mskB = (KB >> 6) - 1;               // power-of-two tile counts only

  const int sr = tid >> 3;
  const int sc = ((tid & 7) ^ (sr & 7)) << 3;
  const unsigned short* gA = A + (size_t)(m0 + sr) * K + sc;
  const unsigned short* gB = BT + (size_t)(n0 + sr) * KB + sc;

  const int swl = (lr & 7) << 3;
  const int cA0 = (lq * 8) ^ swl;
  const int cA1 = (32 + lq * 8) ^ swl;
  const int arow = (wm * 128 + lr) * 64;
  const int brow = (wn * 64 + lr) * 64;

  ffrag4 acc[8][4] = {};
  bfrag8 bfr[4][2];

  auto stage = [&](int bb, int mat, int h, int kt) {
    const int kk = mat ? (kt & mskB) : kt;
    const int str = mat ? KB : K;
    const unsigned short* g = (mat ? gB : gA) + (size_t)(h * 128) * str + (size_t)kk * 64;
    unsigned short* l = &lds[bb][mat][h * 8192 + tid * 8];
    gload16(g, l);
    gload16(g + (size_t)64 * str, l + 4096);
  };

  stage(0, 0, 0, 0); stage(0, 0, 1, 0);
  stage(0, 1, 0, 0); stage(0, 1, 1, 0);
  stage(1, 1, 0, 1); stage(1, 1, 1, 1);
  asm volatile("s_waitcnt vmcnt(4)" ::: "memory");
  __builtin_amdgcn_s_barrier();

  for (int t = 0; t < nkt; ++t) {
    const int b = t & 1;
    const int bn = b ^ 1;
    GPHASE(0, { if (t + 1 < nkt) stage(bn, 0, 0, t + 1); }, {})
    GPHASE(1, { if (t + 1 < nkt) stage(bn, 0, 1, t + 1); }, {})
    GPHASE(2, { if (t + 2 < nkt) stage(b, 1, 0, t + 2); }, {})
    GPHASE(3, { if (t + 2 < nkt) stage(b, 1, 1, t + 2); },
           { if (t < nkt - 2) { asm volatile("s_waitcnt vmcnt(4)" ::: "memory"); }
             else             { asm volatile("s_waitcnt vmcnt(0)" ::: "memory"); } })
  }

  #pragma unroll
  for (int i = 0; i < 8; i++) {
    const int row = m0 + wm * 128 + i * 16 + lq * 4;
    #pragma unroll
    for (int j = 0; j < 4; j++) {
      const int col = n0 + wn * 64 + j * 16 + lr;
      const float bb = BIAS ? bias[col] : 0.f;
      #pragma unroll
      for (int r = 0; r < 4; r++) {
        const float val = acc[i][j][r] + bb;
        if constexpr (sizeof(OutT) == 2) C[(size_t)(row + r) * N + col] = (OutT)f2bf(val);
        else                             C[(size_t)(row + r) * N + col] = (OutT)val;
      }
    }
  }
}

// ---------- Stage A: MFMA k-feature + partial kv/ksum ----------
__global__ __launch_bounds__(256, 1)
void kv_mfma_kernel(const unsigned short* __restrict__ qkv,
                    const unsigned short* __restrict__ projT,  // [H][256f][64d] bf16
                    float* __restrict__ partial) {
  const int c = blockIdx.x, bh = blockIdx.y;
  const int b = bh >> 4, h = bh & 15;
  const int tid = threadIdx.x;
  const int w = tid >> 6, lane = tid & 63;
  const int lq = lane >> 4, lr = lane & 15;
  __shared__ unsigned short pT[256 * 72];   // P^T [f][d], stride 72
  __shared__ unsigned short kp[256 * 72];   // k'  [f][t], stride 72
  __shared__ unsigned short vT[80 * 72];    // V^T [d][t] (+ones row 64), stride 72
  __shared__ float wmax[64][4];
  __shared__ float rmax_s[64];

  #pragma unroll
  for (int e = 0; e < 8; e++) {
    const int job = e * 256 + tid;
    const int f = job >> 3, d0 = (job & 7) * 8;
    const u16x8 v = *(const u16x8*)&projT[(size_t)h * (NF * HD) + f * 64 + d0];
    *(u16x8*)&pT[f * 72 + d0] = v;
  }
  for (int idx = tid; idx < 16 * 72; idx += 256) {
    const int r = idx / 72, cc = idx % 72;
    vT[(64 + r) * 72 + cc] = (r == 0 && cc < 64) ? (unsigned short)0x3F80 : (unsigned short)0;
  }
  __syncthreads();

  ffrag4 acc2[4][5];
  #pragma unroll
  for (int i = 0; i < 4; i++)
    #pragma unroll
    for (int j = 0; j < 5; j++) acc2[i][j] = (ffrag4){0.f, 0.f, 0.f, 0.f};

  const size_t rowbase = (size_t)b * TSEQ + (size_t)c * CH_T;

  for (int tt = 0; tt < CH_T / 64; tt++) {
    const int t0 = tt * 64;
    #pragma unroll
    for (int e = 0; e < 2; e++) {
      const int job = e * 256 + tid;
      const int t = job >> 3, d0 = (job & 7) * 8;
      const u16x8 v = *(const u16x8*)&qkv[(rowbase + t0 + t) * QKV_N + 2048 + h * 64 + d0];
      #pragma unroll
      for (int q = 0; q < 8; q++) vT[(d0 + q) * 72 + t] = v[q];
    }
    ffrag4 accZ[4][4];
    #pragma unroll
    for (int i = 0; i < 4; i++)
      #pragma unroll
      for (int j = 0; j < 4; j++) accZ[i][j] = (ffrag4){0.f, 0.f, 0.f, 0.f};
    #pragma unroll
    for (int kc = 0; kc < 2; kc++) {
      bfrag8 af[4], bfg[4];
      #pragma unroll
      for (int i = 0; i < 4; i++)
        af[i] = *(const bfrag8*)&qkv[(rowbase + t0 + i * 16 + lr) * QKV_N + 1024 + h * 64 + kc * 32 + lq * 8];
      #pragma unroll
      for (int j = 0; j < 4; j++)
        bfg[j] = *(const bfrag8*)&pT[(w * 64 + j * 16 + lr) * 72 + kc * 32 + lq * 8];
      #pragma unroll
      for (int i = 0; i < 4; i++)
        #pragma unroll
        for (int j = 0; j < 4; j++)
          accZ[i][j] = __builtin_amdgcn_mfma_f32_16x16x32_bf16(af[i], bfg[j], accZ[i][j], 0, 0, 0);
    }
    float pmx[4][4];
    #pragma unroll
    for (int i = 0; i < 4; i++)
      #pragma unroll
      for (int r = 0; r < 4; r++) {
        float m = accZ[i][0][r];
        m = fmaxf(m, accZ[i][1][r]); m = fmaxf(m, accZ[i][2][r]); m = fmaxf(m, accZ[i][3][r]);
        pmx[i][r] = m;
      }
    #pragma unroll
    for (int off = 1; off < 16; off <<= 1)
      #pragma unroll
      for (int i = 0; i < 4; i++)
        #pragma unroll
        for (int r = 0; r < 4; r++)
          pmx[i][r] = fmaxf(pmx[i][r], __shfl_xor(pmx[i][r], off, 64));
    if (lr == 0)
      #pragma unroll
      for (int i = 0; i < 4; i++)
        #pragma unroll
        for (int r = 0; r < 4; r++) wmax[i * 16 + lq * 4 + r][w] = pmx[i][r];
    __syncthreads();
    if (tid < 64)
      rmax_s[tid] = fmaxf(fmaxf(wmax[tid][0], wmax[tid][1]), fmaxf(wmax[tid][2], wmax[tid][3]));
    __syncthreads();
    #pragma unroll
    for (int i = 0; i < 4; i++) {
      const float4 rmv = *(const float4*)&rmax_s[i * 16 + lq * 4];
      const float rmarr[4] = {rmv.x, rmv.y, rmv.z, rmv.w};
      #pragma unroll
      for (int j = 0; j < 4; j++) {
        u16x4 pk;
        #pragma unroll
        for (int r = 0; r < 4; r++) pk[r] = f2bf(__expf(accZ[i][j][r] - rmarr[r]));
        *(u16x4*)&kp[(w * 64 + j * 16 + lr) * 72 + i * 16 + lq * 4] = pk;
      }
    }
    __syncthreads();
    #pragma unroll
    for (int kc = 0; kc < 2; kc++) {
      bfrag8 af2[4], bf2[5];
      #pragma unroll
      for (int i = 0; i < 4; i++)
        af2[i] = *(const bfrag8*)&kp[(w * 64 + i * 16 + lr) * 72 + kc * 32 + lq * 8];
      #pragma unroll
      for (int j = 0; j < 5; j++)
        bf2[j] = *(const bfrag8*)&vT[(j * 16 + lr) * 72 + kc * 32 + lq * 8];
      #pragma unroll
      for (int i = 0; i < 4; i++)
        #pragma unroll
        for (int j = 0; j < 5; j++)
          acc2[i][j] = __builtin_amdgcn_mfma_f32_16x16x32_bf16(af2[i], bf2[j], acc2[i][j], 0, 0, 0);
    }
    __syncthreads();
  }
  float* pbase = partial + (size_t)(bh * NCHUNK + c) * NF * KVS;
  #pragma unroll
  for (int i = 0; i < 4; i++)
    #pragma unroll
    for (int j = 0; j < 5; j++) {
      if (j == 4 && lr != 0) continue;
      const int col = j * 16 + lr;
      #pragma unroll
      for (int r = 0; r < 4; r++)
        pbase[(size_t)(w * 64 + i * 16 + lq * 4 + r) * KVS + col] = acc2[i][j][r];
    }
}

// ---------------- reduce kv partials over 8 chunks ----------------
__global__ __launch_bounds__(256)
void kv_reduce_kernel(const float* __restrict__ partial, float* __restrict__ kv) {
  const size_t i = (size_t)blockIdx.x * 256 + threadIdx.x;
  const size_t per_bh = (size_t)NF * KVS;
  const size_t bh = i / per_bh;
  const size_t j = i % per_bh;
  const float* p = partial + bh * NCHUNK * per_bh + j;
  float s = 0.f;
  #pragma unroll
  for (int c = 0; c < NCHUNK; c++) s += p[c * per_bh];
  kv[i] = s;
}

// ---------- Stage B: MFMA q-feature + O = q' @ [KV | ksum] + normalize ----------
// grid (NCHUNK, B*H) — each block owns 512 tokens (8 x 64-token subtiles).
// KV^T staged in LDS once per block; P fragments hoisted to registers.
__global__ __launch_bounds__(256, 2)
void q_attn_mfma_kernel(const unsigned short* __restrict__ qkv,
                        const unsigned short* __restrict__ projT,
                        const float* __restrict__ kv,
                        unsigned short* __restrict__ attn) {
  const int c = blockIdx.x, bh = blockIdx.y;
  const int b = bh >> 4, h = bh & 15;
  const int tid = threadIdx.x;
  const int w = tid >> 6, lane = tid & 63;
  const int lq = lane >> 4, lr = lane & 15;
  __shared__ unsigned short qp[64 * 264];    // q' [t][f], stride 264
  __shared__ unsigned short kvT[80 * 264];   // KV^T [d][f] (+ksum row 64)
  __shared__ float wmax[64][4];
  __shared__ float rmax_s[64];

  {
    const float* kvrow = kv + ((size_t)bh * NF + tid) * KVS;
    #pragma unroll
    for (int d0 = 0; d0 < 64; d0 += 4) {
      const float4 v = *(const float4*)&kvrow[d0];
      kvT[(d0 + 0) * 264 + tid] = f2bf(v.x);
      kvT[(d0 + 1) * 264 + tid] = f2bf(v.y);
      kvT[(d0 + 2) * 264 + tid] = f2bf(v.z);
      kvT[(d0 + 3) * 264 + tid] = f2bf(v.w);
    }
    kvT[64 * 264 + tid] = f2bf(kvrow[64]);
    for (int idx = tid; idx < 15 * 264; idx += 256)
      kvT[65 * 264 + idx] = 0;
  }
  const unsigned short* pTg = projT + (size_t)h * (NF * HD);
  bfrag8 bfg[2][4];
  #pragma unroll
  for (int kc = 0; kc < 2; kc++)
    #pragma unroll
    for (int j = 0; j < 4; j++)
      bfg[kc][j] = *(const bfrag8*)&pTg[(size_t)(w * 64 + j * 16 + lr) * 64 + kc * 32 + lq * 8];
  __syncthreads();

  for (int tt = 0; tt < CH_T / 64; tt++) {
    const size_t rowbase = (size_t)b * TSEQ + (size_t)c * CH_T + (size_t)tt * 64;
    ffrag4 accZ[4][4];
    #pragma unroll
    for (int i = 0; i < 4; i++)
      #pragma unroll
      for (int j = 0; j < 4; j++) accZ[i][j] = (ffrag4){0.f, 0.f, 0.f, 0.f};
    #pragma unroll
    for (int kc = 0; kc < 2; kc++) {
      bfrag8 af[4];
      #pragma unroll
      for (int i = 0; i < 4; i++)
        af[i] = *(const bfrag8*)&qkv[(rowbase + i * 16 + lr) * QKV_N + 0 + h * 64 + kc * 32 + lq * 8];
      #pragma unroll
      for (int i = 0; i < 4; i++)
        #pragma unroll
        for (int j = 0; j < 4; j++)
          accZ[i][j] = __builtin_amdgcn_mfma_f32_16x16x32_bf16(af[i], bfg[kc][j], accZ[i][j], 0, 0, 0);
    }
    float pmx[4][4];
    #pragma unroll
    for (int i = 0; i < 4; i++)
      #pragma unroll
      for (int r = 0; r < 4; r++) {
        float m = accZ[i][0][r];
        m = fmaxf(m, accZ[i][1][r]); m = fmaxf(m, accZ[i][2][r]); m = fmaxf(m, accZ[i][3][r]);
        pmx[i][r] = m;
      }
    #pragma unroll
    for (int off = 1; off < 16; off <<= 1)
      #pragma unroll
      for (int i = 0; i < 4; i++)
        #pragma unroll
        for (int r = 0; r < 4; r++)
          pmx[i][r] = fmaxf(pmx[i][r], __shfl_xor(pmx[i][r], off, 64));
    if (lr == 0)
      #pragma unroll
      for (int i = 0; i < 4; i++)
        #pragma unroll
        for (int r = 0; r < 4; r++) wmax[i * 16 + lq * 4 + r][w] = pmx[i][r];
    __syncthreads();
    if (tid < 64)
      rmax_s[tid] = fmaxf(fmaxf(wmax[tid][0], wmax[tid][1]), fmaxf(wmax[tid][2], wmax[tid][3]));
    __syncthreads();
    #pragma unroll
    for (int i = 0; i < 4; i++) {
      const float4 rmv = *(const float4*)&rmax_s[i * 16 + lq * 4];
      const float rmarr[4] = {rmv.x, rmv.y, rmv.z, rmv.w};
      #pragma unroll
      for (int j = 0; j < 4; j++)
        #pragma unroll
        for (int r = 0; r < 4; r++)
          qp[(i * 16 + lq * 4 + r) * 264 + w * 64 + j * 16 + lr] = f2bf(__expf(accZ[i][j][r] - rmarr[r]));
    }
    __syncthreads();
    ffrag4 acc3[5];
    #pragma unroll
    for (int j = 0; j < 5; j++) acc3[j] = (ffrag4){0.f, 0.f, 0.f, 0.f};
    #pragma unroll
    for (int kc = 0; kc < 8; kc++) {
      const bfrag8 afq = *(const bfrag8*)&qp[(w * 16 + lr) * 264 + kc * 32 + lq * 8];
      #pragma unroll
      for (int j = 0; j < 5; j++) {
        const bfrag8 bf3 = *(const bfrag8*)&kvT[(j * 16 + lr) * 264 + kc * 32 + lq * 8];
        acc3[j] = __builtin_amdgcn_mfma_f32_16x16x32_bf16(afq, bf3, acc3[j], 0, 0, 0);
      }
    }
    #pragma unroll
    for (int r = 0; r < 4; r++) {
      const float den = __shfl(acc3[4][r], lane & 48, 64);
      const float z = 1.f / (den + 1e-6f);
      const int t = c * CH_T + tt * 64 + w * 16 + lq * 4 + r;
      unsigned short* orow = attn + ((size_t)b * TSEQ + t) * DIM_ + h * 64;
      #pragma unroll
      for (int j = 0; j < 4; j++)
        orow[j * 16 + lr] = f2bf(acc3[j][r] * z);
    }
    __syncthreads();
  }
}

extern "C" void kernel_launch(void* const* d_in, const int* in_sizes, int n_in,
                              void* d_out, int out_size, void* d_ws, size_t ws_size,
                              hipStream_t stream) {
  const float* x     = (const float*)d_in[0];
  const float* w_qkv = (const float*)d_in[1];
  const float* w_out = (const float*)d_in[2];
  const float* b_out = (const float*)d_in[3];
  const float* proj  = (const float*)d_in[4];
  float* out = (float*)d_out;

  char* ws = (char*)d_ws;
  // Common phase-2 layout (reuses region freed after the qkv GEMM):
  //   [0,          100663296)  qkv bf16 (16384*3072)
  //   [100663296,  136314880)  partial fp32 (64*8*256*68)    — then:
  //   [100663296,  134217728)  attn bf16 (16384*1024)
  //   [134217728,  136314880)  woutT bf16 (1024*1024)
  //   [136314880,  140771328)  kv fp32 (64*256*68)
  unsigned short* qkv    = (unsigned short*)ws;
  float*          partial= (float*)(ws + 100663296);
  unsigned short* attn   = (unsigned short*)(ws + 100663296);
  unsigned short* woutT  = (unsigned short*)(ws + 134217728);
  float*          kvbuf  = (float*)(ws + 136314880);

  // FULL path: A2 covers all of x (one qkv GEMM dispatch, 768 blocks = 3 clean rounds).
  //   [100663296, 167772160)  A2 bf16 (16384*2048)
  //   [167772160, 174063616)  wqkvT bf16 (3072*1024)  (un-duplicated; B K-tiles wrap)
  //   [174063616, 174587904)  projT bf16
  // FALLBACK path (ws too small): two M-halves sharing one 33.5 MB A2.
  //   [100663296, 134217728)  A2 half
  //   [134217728, 140509184)  wqkvT
  //   [140771328, 141295616)  projT (after kv, both alive in phase 2)
  const bool full = ws_size >= 174587904ULL;
  unsigned short* a2    = (unsigned short*)(ws + 100663296);
  unsigned short* wqkvT = (unsigned short*)(ws + (full ? 167772160 : 134217728));
  unsigned short* projT = (unsigned short*)(ws + (full ? 174063616 : 140771328));

  transpose_cast<<<dim3(QKV_N/32, DIM_/32, 1), 256, 0, stream>>>(w_qkv, wqkvT, DIM_, QKV_N);
  transpose_cast<<<dim3(NF/32, HD/32, NH), 256, 0, stream>>>(proj, projT, HD, NF);

  // 1) qkv = x @ w_qkv as bf16 K=2048 GEMM over hi|lo planes (B wraps mod 1024)
  if (full) {
    split_cast<<<8192, 256, 0, stream>>>(x, a2);
    gemm256<false, unsigned short><<<768, 512, 0, stream>>>(
        a2, wqkvT, nullptr, qkv, TOK, QKV_N, 2048, 1024);
  } else {
    for (int hh = 0; hh < 2; ++hh) {
      split_cast<<<4096, 256, 0, stream>>>(x + (size_t)hh * 8192 * DIM_, a2);
      gemm256<false, unsigned short><<<384, 512, 0, stream>>>(
          a2, wqkvT, nullptr, qkv + (size_t)hh * 8192 * QKV_N, 8192, QKV_N, 2048, 1024);
    }
  }
  // 2) MFMA k-feature + partial kv/ksum
  kv_mfma_kernel<<<dim3(NCHUNK, 64), 256, 0, stream>>>(qkv, projT, partial);
  // 3) reduce partials
  kv_reduce_kernel<<<dim3(64*NF*KVS/256), 256, 0, stream>>>(partial, kvbuf);
  // 4) woutT (into region freed by reduce)
  transpose_cast<<<dim3(DIM_/32, DIM_/32, 1), 256, 0, stream>>>(w_out, woutT, DIM_, DIM_);
  // 5) MFMA q-feature + q'@kv + normalize -> attn bf16
  q_attn_mfma_kernel<<<dim3(NCHUNK, 64), 256, 0, stream>>>(qkv, projT, kvbuf, attn);
  // 6) out = attn @ w_out + b_out
  gemm256<true, float><<<256, 512, 0, stream>>>(attn, woutT, b_out, out, TOK, DIM_, DIM_, DIM_);
}

// Round 4
// 466.311 us; speedup vs baseline: 1.3503x; 1.0729x over previous
//
#include <hip/hip_runtime.h>

#define TOK   16384   // B*T
#define DIM_  1024
#define QKV_N 3072
#define NH    16
#define HD    64
#define NF    256
#define TSEQ  4096
#define NCHUNK 8
#define CH_T  512     // TSEQ/NCHUNK
#define KVS   68      // kv row stride (64 d + 1 ksum + pad)

typedef __attribute__((ext_vector_type(8))) short  bfrag8;   // 8 bf16 (4 VGPRs)
typedef __attribute__((ext_vector_type(4))) float  ffrag4;   // 4 fp32 acc
typedef __attribute__((ext_vector_type(8))) unsigned short u16x8;
typedef __attribute__((ext_vector_type(4))) unsigned short u16x4;

__device__ __forceinline__ float bf2f(unsigned short u) {
  union { unsigned int i; float f; } c; c.i = ((unsigned int)u) << 16; return c.f;
}
__device__ __forceinline__ unsigned short f2bf(float f) {
  union { float f; unsigned int i; } c; c.f = f;
  unsigned int r = c.i + 0x7FFFu + ((c.i >> 16) & 1u);
  return (unsigned short)(r >> 16);
}

__device__ __forceinline__ void gload16(const unsigned short* g, unsigned short* l) {
  __builtin_amdgcn_global_load_lds(
      (const __attribute__((address_space(1))) unsigned int*)g,
      (__attribute__((address_space(3))) unsigned int*)l, 16, 0, 0);
}

// ---------------- batched transpose + cast fp32 [R][C] -> bf16 [C][R] ----------------
__global__ __launch_bounds__(256)
void transpose_cast(const float* __restrict__ in, unsigned short* __restrict__ out,
                    int R, int C) {
  __shared__ float tile[32][33];
  const size_t batch_off = (size_t)blockIdx.z * R * C;
  const float* bin = in + batch_off;
  unsigned short* bout = out + batch_off;
  const int bc = blockIdx.x * 32, br = blockIdx.y * 32;
  const int tx = threadIdx.x & 31, ty = threadIdx.x >> 5;   // 32x8
  #pragma unroll
  for (int i = 0; i < 32; i += 8)
    tile[ty + i][tx] = bin[(size_t)(br + ty + i) * C + bc + tx];
  __syncthreads();
  #pragma unroll
  for (int i = 0; i < 32; i += 8)
    bout[(size_t)(bc + ty + i) * R + br + tx] = f2bf(tile[tx][ty + i]);
}

// ---------------- fp32 x [rows][1024] -> bf16 hi/lo split A2 [rows][2048] ----------------
// A2[:,0:1024] = truncate-to-bf16(x), A2[:,1024:2048] = round-to-bf16(x - hi).
__global__ __launch_bounds__(256)
void split_cast(const float* __restrict__ x, unsigned short* __restrict__ a2) {
  const size_t idx = ((size_t)blockIdx.x * 256 + threadIdx.x) * 8;
  const size_t r = idx >> 10;
  const int c = (int)(idx & 1023);
  const float4 v0 = *(const float4*)&x[idx];
  const float4 v1 = *(const float4*)&x[idx + 4];
  const float f[8] = {v0.x, v0.y, v0.z, v0.w, v1.x, v1.y, v1.z, v1.w};
  u16x8 hi, lo;
  #pragma unroll
  for (int e = 0; e < 8; e++) {
    union { float f; unsigned u; } cc; cc.f = f[e];
    const unsigned short h = (unsigned short)(cc.u >> 16);
    union { unsigned u; float f; } hb; hb.u = ((unsigned)h) << 16;
    hi[e] = h; lo[e] = f2bf(f[e] - hb.f);
  }
  *(u16x8*)&a2[r * 2048 + c] = hi;
  *(u16x8*)&a2[r * 2048 + 1024 + c] = lo;
}

// ---------------- 256x256 8-phase bf16 GEMM (T1+T2+T3+T4+T5) ----------------
// C[M][N] = A[M][K] @ BT[N][KB]^T (+bias), with B K-tiles wrapped mod KB/64.
// v4: lgkmcnt drain moved AFTER the MFMA cluster (before phase-end barrier).
// ds_reads are compiler-emitted (not inline-asm), so the compiler inserts
// fine-grained per-MFMA lgkmcnt waits; the end-of-phase drain only guarantees
// no outstanding ds_read crosses a barrier into a phase whose STG overwrites
// the region (ph0 B-reads vs ph2 B-stage; ph3 A-reads vs next-iter A-stage).
#define GPHASE(Q, STG, VMW)                                                        \
  {                                                                                \
    const int ab = arow + (Q) * 2048;                                              \
    bfrag8 a00 = *(const bfrag8*)&lds[b][0][ab + cA0];                             \
    bfrag8 a01 = *(const bfrag8*)&lds[b][0][ab + cA1];                             \
    bfrag8 a10 = *(const bfrag8*)&lds[b][0][ab + 1024 + cA0];                      \
    bfrag8 a11 = *(const bfrag8*)&lds[b][0][ab + 1024 + cA1];                      \
    if ((Q) == 0) {                                                                \
      _Pragma("unroll")                                                            \
      for (int j = 0; j < 4; j++) {                                                \
        bfr[j][0] = *(const bfrag8*)&lds[b][1][brow + j * 1024 + cA0];             \
        bfr[j][1] = *(const bfrag8*)&lds[b][1][brow + j * 1024 + cA1];             \
      }                                                                            \
    }                                                                              \
    STG;                                                                           \
    __builtin_amdgcn_s_barrier();                                                  \
    __builtin_amdgcn_s_setprio(1);                                                 \
    _Pragma("unroll")                                                              \
    for (int j = 0; j < 4; j++) {                                                  \
      acc[(Q)*2][j]   = __builtin_amdgcn_mfma_f32_16x16x32_bf16(a00, bfr[j][0], acc[(Q)*2][j], 0, 0, 0);   \
      acc[(Q)*2][j]   = __builtin_amdgcn_mfma_f32_16x16x32_bf16(a01, bfr[j][1], acc[(Q)*2][j], 0, 0, 0);   \
      acc[(Q)*2+1][j] = __builtin_amdgcn_mfma_f32_16x16x32_bf16(a10, bfr[j][0], acc[(Q)*2+1][j], 0, 0, 0); \
      acc[(Q)*2+1][j] = __builtin_amdgcn_mfma_f32_16x16x32_bf16(a11, bfr[j][1], acc[(Q)*2+1][j], 0, 0, 0); \
    }                                                                              \
    __builtin_amdgcn_s_setprio(0);                                                 \
    asm volatile("s_waitcnt lgkmcnt(0)" ::: "memory");                             \
    VMW;                                                                           \
    __builtin_amdgcn_s_barrier();                                                  \
  }

template<bool BIAS, typename OutT>
__global__ __launch_bounds__(512, 2)
void gemm256(const unsigned short* __restrict__ A,
             const unsigned short* __restrict__ BT,
             const float* __restrict__ bias, OutT* __restrict__ C,
             int M, int N, int K, int KB) {
  __shared__ alignas(16) unsigned short lds[2][2][256 * 64];
  const int tid = threadIdx.x;
  const int w = tid >> 6, lane = tid & 63;
  const int wm = w >> 2, wn = w & 3;            // 2 x 4 waves
  const int lq = lane >> 4, lr = lane & 15;

  const int nbx = N >> 8;
  const int cpx = (int)gridDim.x >> 3;
  const int bid = (int)blockIdx.x;
  const int swz = (bid & 7) * cpx + (bid >> 3);
  const int m0 = (swz / nbx) << 8;
  const int n0 = (swz % nbx) << 8;
  const int nkt = K >> 6;
  const int mskB = (KB >> 6) - 1;               // power-of-two tile counts only

  const int sr = tid >> 3;
  const int sc = ((tid & 7) ^ (sr & 7)) << 3;
  const unsigned short* gA = A + (size_t)(m0 + sr) * K + sc;
  const unsigned short* gB = BT + (size_t)(n0 + sr) * KB + sc;

  const int swl = (lr & 7) << 3;
  const int cA0 = (lq * 8) ^ swl;
  const int cA1 = (32 + lq * 8) ^ swl;
  const int arow = (wm * 128 + lr) * 64;
  const int brow = (wn * 64 + lr) * 64;

  ffrag4 acc[8][4] = {};
  bfrag8 bfr[4][2];

  auto stage = [&](int bb, int mat, int h, int kt) {
    const int kk = mat ? (kt & mskB) : kt;
    const int str = mat ? KB : K;
    const unsigned short* g = (mat ? gB : gA) + (size_t)(h * 128) * str + (size_t)kk * 64;
    unsigned short* l = &lds[bb][mat][h * 8192 + tid * 8];
    gload16(g, l);
    gload16(g + (size_t)64 * str, l + 4096);
  };

  stage(0, 0, 0, 0); stage(0, 0, 1, 0);
  stage(0, 1, 0, 0); stage(0, 1, 1, 0);
  stage(1, 1, 0, 1); stage(1, 1, 1, 1);
  asm volatile("s_waitcnt vmcnt(4)" ::: "memory");
  __builtin_amdgcn_s_barrier();

  for (int t = 0; t < nkt; ++t) {
    const int b = t & 1;
    const int bn = b ^ 1;
    GPHASE(0, { if (t + 1 < nkt) stage(bn, 0, 0, t + 1); }, {})
    GPHASE(1, { if (t + 1 < nkt) stage(bn, 0, 1, t + 1); }, {})
    GPHASE(2, { if (t + 2 < nkt) stage(b, 1, 0, t + 2); }, {})
    GPHASE(3, { if (t + 2 < nkt) stage(b, 1, 1, t + 2); },
           { if (t < nkt - 2) { asm volatile("s_waitcnt vmcnt(4)" ::: "memory"); }
             else             { asm volatile("s_waitcnt vmcnt(0)" ::: "memory"); } })
  }

  #pragma unroll
  for (int i = 0; i < 8; i++) {
    const int row = m0 + wm * 128 + i * 16 + lq * 4;
    #pragma unroll
    for (int j = 0; j < 4; j++) {
      const int col = n0 + wn * 64 + j * 16 + lr;
      const float bb = BIAS ? bias[col] : 0.f;
      #pragma unroll
      for (int r = 0; r < 4; r++) {
        const float val = acc[i][j][r] + bb;
        if constexpr (sizeof(OutT) == 2) C[(size_t)(row + r) * N + col] = (OutT)f2bf(val);
        else                             C[(size_t)(row + r) * N + col] = (OutT)val;
      }
    }
  }
}

// ---------- Stage A: MFMA k-feature + partial kv/ksum ----------
// v4: P fragments hoisted to registers (pT LDS dropped, ~50 KB LDS) -> 2 blocks/CU.
__global__ __launch_bounds__(256, 2)
void kv_mfma_kernel(const unsigned short* __restrict__ qkv,
                    const unsigned short* __restrict__ projT,  // [H][256f][64d] bf16
                    float* __restrict__ partial) {
  const int c = blockIdx.x, bh = blockIdx.y;
  const int b = bh >> 4, h = bh & 15;
  const int tid = threadIdx.x;
  const int w = tid >> 6, lane = tid & 63;
  const int lq = lane >> 4, lr = lane & 15;
  __shared__ unsigned short kp[256 * 72];   // k'  [f][t], stride 72
  __shared__ unsigned short vT[80 * 72];    // V^T [d][t] (+ones row 64), stride 72
  __shared__ float wmax[64][4];
  __shared__ float rmax_s[64];

  // hoist P fragments: constant per block (same pattern as q_attn kernel)
  const unsigned short* pTg = projT + (size_t)h * (NF * HD);
  bfrag8 bfgP[2][4];
  #pragma unroll
  for (int kc = 0; kc < 2; kc++)
    #pragma unroll
    for (int j = 0; j < 4; j++)
      bfgP[kc][j] = *(const bfrag8*)&pTg[(size_t)(w * 64 + j * 16 + lr) * 64 + kc * 32 + lq * 8];

  for (int idx = tid; idx < 16 * 72; idx += 256) {
    const int r = idx / 72, cc = idx % 72;
    vT[(64 + r) * 72 + cc] = (r == 0 && cc < 64) ? (unsigned short)0x3F80 : (unsigned short)0;
  }
  __syncthreads();

  ffrag4 acc2[4][5];
  #pragma unroll
  for (int i = 0; i < 4; i++)
    #pragma unroll
    for (int j = 0; j < 5; j++) acc2[i][j] = (ffrag4){0.f, 0.f, 0.f, 0.f};

  const size_t rowbase = (size_t)b * TSEQ + (size_t)c * CH_T;

  for (int tt = 0; tt < CH_T / 64; tt++) {
    const int t0 = tt * 64;
    #pragma unroll
    for (int e = 0; e < 2; e++) {
      const int job = e * 256 + tid;
      const int t = job >> 3, d0 = (job & 7) * 8;
      const u16x8 v = *(const u16x8*)&qkv[(rowbase + t0 + t) * QKV_N + 2048 + h * 64 + d0];
      #pragma unroll
      for (int q = 0; q < 8; q++) vT[(d0 + q) * 72 + t] = v[q];
    }
    ffrag4 accZ[4][4];
    #pragma unroll
    for (int i = 0; i < 4; i++)
      #pragma unroll
      for (int j = 0; j < 4; j++) accZ[i][j] = (ffrag4){0.f, 0.f, 0.f, 0.f};
    #pragma unroll
    for (int kc = 0; kc < 2; kc++) {
      bfrag8 af[4];
      #pragma unroll
      for (int i = 0; i < 4; i++)
        af[i] = *(const bfrag8*)&qkv[(rowbase + t0 + i * 16 + lr) * QKV_N + 1024 + h * 64 + kc * 32 + lq * 8];
      #pragma unroll
      for (int i = 0; i < 4; i++)
        #pragma unroll
        for (int j = 0; j < 4; j++)
          accZ[i][j] = __builtin_amdgcn_mfma_f32_16x16x32_bf16(af[i], bfgP[kc][j], accZ[i][j], 0, 0, 0);
    }
    float pmx[4][4];
    #pragma unroll
    for (int i = 0; i < 4; i++)
      #pragma unroll
      for (int r = 0; r < 4; r++) {
        float m = accZ[i][0][r];
        m = fmaxf(m, accZ[i][1][r]); m = fmaxf(m, accZ[i][2][r]); m = fmaxf(m, accZ[i][3][r]);
        pmx[i][r] = m;
      }
    #pragma unroll
    for (int off = 1; off < 16; off <<= 1)
      #pragma unroll
      for (int i = 0; i < 4; i++)
        #pragma unroll
        for (int r = 0; r < 4; r++)
          pmx[i][r] = fmaxf(pmx[i][r], __shfl_xor(pmx[i][r], off, 64));
    if (lr == 0)
      #pragma unroll
      for (int i = 0; i < 4; i++)
        #pragma unroll
        for (int r = 0; r < 4; r++) wmax[i * 16 + lq * 4 + r][w] = pmx[i][r];
    __syncthreads();
    if (tid < 64)
      rmax_s[tid] = fmaxf(fmaxf(wmax[tid][0], wmax[tid][1]), fmaxf(wmax[tid][2], wmax[tid][3]));
    __syncthreads();
    #pragma unroll
    for (int i = 0; i < 4; i++) {
      const float4 rmv = *(const float4*)&rmax_s[i * 16 + lq * 4];
      const float rmarr[4] = {rmv.x, rmv.y, rmv.z, rmv.w};
      #pragma unroll
      for (int j = 0; j < 4; j++) {
        u16x4 pk;
        #pragma unroll
        for (int r = 0; r < 4; r++) pk[r] = f2bf(__expf(accZ[i][j][r] - rmarr[r]));
        *(u16x4*)&kp[(w * 64 + j * 16 + lr) * 72 + i * 16 + lq * 4] = pk;
      }
    }
    __syncthreads();
    #pragma unroll
    for (int kc = 0; kc < 2; kc++) {
      bfrag8 af2[4], bf2[5];
      #pragma unroll
      for (int i = 0; i < 4; i++)
        af2[i] = *(const bfrag8*)&kp[(w * 64 + i * 16 + lr) * 72 + kc * 32 + lq * 8];
      #pragma unroll
      for (int j = 0; j < 5; j++)
        bf2[j] = *(const bfrag8*)&vT[(j * 16 + lr) * 72 + kc * 32 + lq * 8];
      #pragma unroll
      for (int i = 0; i < 4; i++)
        #pragma unroll
        for (int j = 0; j < 5; j++)
          acc2[i][j] = __builtin_amdgcn_mfma_f32_16x16x32_bf16(af2[i], bf2[j], acc2[i][j], 0, 0, 0);
    }
    __syncthreads();
  }
  float* pbase = partial + (size_t)(bh * NCHUNK + c) * NF * KVS;
  #pragma unroll
  for (int i = 0; i < 4; i++)
    #pragma unroll
    for (int j = 0; j < 5; j++) {
      if (j == 4 && lr != 0) continue;
      const int col = j * 16 + lr;
      #pragma unroll
      for (int r = 0; r < 4; r++)
        pbase[(size_t)(w * 64 + i * 16 + lq * 4 + r) * KVS + col] = acc2[i][j][r];
    }
}

// ---------------- reduce kv partials over 8 chunks ----------------
__global__ __launch_bounds__(256)
void kv_reduce_kernel(const float* __restrict__ partial, float* __restrict__ kv) {
  const size_t i = (size_t)blockIdx.x * 256 + threadIdx.x;
  const size_t per_bh = (size_t)NF * KVS;
  const size_t bh = i / per_bh;
  const size_t j = i % per_bh;
  const float* p = partial + bh * NCHUNK * per_bh + j;
  float s = 0.f;
  #pragma unroll
  for (int c = 0; c < NCHUNK; c++) s += p[c * per_bh];
  kv[i] = s;
}

// ---------- Stage B: MFMA q-feature + O = q' @ [KV | ksum] + normalize ----------
// grid (NCHUNK, B*H) — each block owns 512 tokens (8 x 64-token subtiles).
// KV^T staged in LDS once per block; P fragments hoisted to registers.
__global__ __launch_bounds__(256, 2)
void q_attn_mfma_kernel(const unsigned short* __restrict__ qkv,
                        const unsigned short* __restrict__ projT,
                        const float* __restrict__ kv,
                        unsigned short* __restrict__ attn) {
  const int c = blockIdx.x, bh = blockIdx.y;
  const int b = bh >> 4, h = bh & 15;
  const int tid = threadIdx.x;
  const int w = tid >> 6, lane = tid & 63;
  const int lq = lane >> 4, lr = lane & 15;
  __shared__ unsigned short qp[64 * 264];    // q' [t][f], stride 264
  __shared__ unsigned short kvT[80 * 264];   // KV^T [d][f] (+ksum row 64)
  __shared__ float wmax[64][4];
  __shared__ float rmax_s[64];

  {
    const float* kvrow = kv + ((size_t)bh * NF + tid) * KVS;
    #pragma unroll
    for (int d0 = 0; d0 < 64; d0 += 4) {
      const float4 v = *(const float4*)&kvrow[d0];
      kvT[(d0 + 0) * 264 + tid] = f2bf(v.x);
      kvT[(d0 + 1) * 264 + tid] = f2bf(v.y);
      kvT[(d0 + 2) * 264 + tid] = f2bf(v.z);
      kvT[(d0 + 3) * 264 + tid] = f2bf(v.w);
    }
    kvT[64 * 264 + tid] = f2bf(kvrow[64]);
    for (int idx = tid; idx < 15 * 264; idx += 256)
      kvT[65 * 264 + idx] = 0;
  }
  const unsigned short* pTg = projT + (size_t)h * (NF * HD);
  bfrag8 bfg[2][4];
  #pragma unroll
  for (int kc = 0; kc < 2; kc++)
    #pragma unroll
    for (int j = 0; j < 4; j++)
      bfg[kc][j] = *(const bfrag8*)&pTg[(size_t)(w * 64 + j * 16 + lr) * 64 + kc * 32 + lq * 8];
  __syncthreads();

  for (int tt = 0; tt < CH_T / 64; tt++) {
    const size_t rowbase = (size_t)b * TSEQ + (size_t)c * CH_T + (size_t)tt * 64;
    ffrag4 accZ[4][4];
    #pragma unroll
    for (int i = 0; i < 4; i++)
      #pragma unroll
      for (int j = 0; j < 4; j++) accZ[i][j] = (ffrag4){0.f, 0.f, 0.f, 0.f};
    #pragma unroll
    for (int kc = 0; kc < 2; kc++) {
      bfrag8 af[4];
      #pragma unroll
      for (int i = 0; i < 4; i++)
        af[i] = *(const bfrag8*)&qkv[(rowbase + i * 16 + lr) * QKV_N + 0 + h * 64 + kc * 32 + lq * 8];
      #pragma unroll
      for (int i = 0; i < 4; i++)
        #pragma unroll
        for (int j = 0; j < 4; j++)
          accZ[i][j] = __builtin_amdgcn_mfma_f32_16x16x32_bf16(af[i], bfg[kc][j], accZ[i][j], 0, 0, 0);
    }
    float pmx[4][4];
    #pragma unroll
    for (int i = 0; i < 4; i++)
      #pragma unroll
      for (int r = 0; r < 4; r++) {
        float m = accZ[i][0][r];
        m = fmaxf(m, accZ[i][1][r]); m = fmaxf(m, accZ[i][2][r]); m = fmaxf(m, accZ[i][3][r]);
        pmx[i][r] = m;
      }
    #pragma unroll
    for (int off = 1; off < 16; off <<= 1)
      #pragma unroll
      for (int i = 0; i < 4; i++)
        #pragma unroll
        for (int r = 0; r < 4; r++)
          pmx[i][r] = fmaxf(pmx[i][r], __shfl_xor(pmx[i][r], off, 64));
    if (lr == 0)
      #pragma unroll
      for (int i = 0; i < 4; i++)
        #pragma unroll
        for (int r = 0; r < 4; r++) wmax[i * 16 + lq * 4 + r][w] = pmx[i][r];
    __syncthreads();
    if (tid < 64)
      rmax_s[tid] = fmaxf(fmaxf(wmax[tid][0], wmax[tid][1]), fmaxf(wmax[tid][2], wmax[tid][3]));
    __syncthreads();
    #pragma unroll
    for (int i = 0; i < 4; i++) {
      const float4 rmv = *(const float4*)&rmax_s[i * 16 + lq * 4];
      const float rmarr[4] = {rmv.x, rmv.y, rmv.z, rmv.w};
      #pragma unroll
      for (int j = 0; j < 4; j++)
        #pragma unroll
        for (int r = 0; r < 4; r++)
          qp[(i * 16 + lq * 4 + r) * 264 + w * 64 + j * 16 + lr] = f2bf(__expf(accZ[i][j][r] - rmarr[r]));
    }
    __syncthreads();
    ffrag4 acc3[5];
    #pragma unroll
    for (int j = 0; j < 5; j++) acc3[j] = (ffrag4){0.f, 0.f, 0.f, 0.f};
    #pragma unroll
    for (int kc = 0; kc < 8; kc++) {
      const bfrag8 afq = *(const bfrag8*)&qp[(w * 16 + lr) * 264 + kc * 32 + lq * 8];
      #pragma unroll
      for (int j = 0; j < 5; j++) {
        const bfrag8 bf3 = *(const bfrag8*)&kvT[(j * 16 + lr) * 264 + kc * 32 + lq * 8];
        acc3[j] = __builtin_amdgcn_mfma_f32_16x16x32_bf16(afq, bf3, acc3[j], 0, 0, 0);
      }
    }
    #pragma unroll
    for (int r = 0; r < 4; r++) {
      const float den = __shfl(acc3[4][r], lane & 48, 64);
      const float z = 1.f / (den + 1e-6f);
      const int t = c * CH_T + tt * 64 + w * 16 + lq * 4 + r;
      unsigned short* orow = attn + ((size_t)b * TSEQ + t) * DIM_ + h * 64;
      #pragma unroll
      for (int j = 0; j < 4; j++)
        orow[j * 16 + lr] = f2bf(acc3[j][r] * z);
    }
    __syncthreads();
  }
}

extern "C" void kernel_launch(void* const* d_in, const int* in_sizes, int n_in,
                              void* d_out, int out_size, void* d_ws, size_t ws_size,
                              hipStream_t stream) {
  const float* x     = (const float*)d_in[0];
  const float* w_qkv = (const float*)d_in[1];
  const float* w_out = (const float*)d_in[2];
  const float* b_out = (const float*)d_in[3];
  const float* proj  = (const float*)d_in[4];
  float* out = (float*)d_out;

  char* ws = (char*)d_ws;
  // Common phase-2 layout (reuses region freed after the qkv GEMM):
  //   [0,          100663296)  qkv bf16 (16384*3072)
  //   [100663296,  136314880)  partial fp32 (64*8*256*68)    — then:
  //   [100663296,  134217728)  attn bf16 (16384*1024)
  //   [134217728,  136314880)  woutT bf16 (1024*1024)
  //   [136314880,  140771328)  kv fp32 (64*256*68)
  unsigned short* qkv    = (unsigned short*)ws;
  float*          partial= (float*)(ws + 100663296);
  unsigned short* attn   = (unsigned short*)(ws + 100663296);
  unsigned short* woutT  = (unsigned short*)(ws + 134217728);
  float*          kvbuf  = (float*)(ws + 136314880);

  // FULL path: A2 covers all of x (one qkv GEMM dispatch, 768 blocks = 3 clean rounds).
  //   [100663296, 167772160)  A2 bf16 (16384*2048)
  //   [167772160, 174063616)  wqkvT bf16 (3072*1024)  (un-duplicated; B K-tiles wrap)
  //   [174063616, 174587904)  projT bf16
  // FALLBACK path (ws too small): two M-halves sharing one 33.5 MB A2.
  const bool full = ws_size >= 174587904ULL;
  unsigned short* a2    = (unsigned short*)(ws + 100663296);
  unsigned short* wqkvT = (unsigned short*)(ws + (full ? 167772160 : 134217728));
  unsigned short* projT = (unsigned short*)(ws + (full ? 174063616 : 140771328));

  transpose_cast<<<dim3(QKV_N/32, DIM_/32, 1), 256, 0, stream>>>(w_qkv, wqkvT, DIM_, QKV_N);
  transpose_cast<<<dim3(NF/32, HD/32, NH), 256, 0, stream>>>(proj, projT, HD, NF);

  // 1) qkv = x @ w_qkv as bf16 K=2048 GEMM over hi|lo planes (B wraps mod 1024)
  if (full) {
    split_cast<<<8192, 256, 0, stream>>>(x, a2);
    gemm256<false, unsigned short><<<768, 512, 0, stream>>>(
        a2, wqkvT, nullptr, qkv, TOK, QKV_N, 2048, 1024);
  } else {
    for (int hh = 0; hh < 2; ++hh) {
      split_cast<<<4096, 256, 0, stream>>>(x + (size_t)hh * 8192 * DIM_, a2);
      gemm256<false, unsigned short><<<384, 512, 0, stream>>>(
          a2, wqkvT, nullptr, qkv + (size_t)hh * 8192 * QKV_N, 8192, QKV_N, 2048, 1024);
    }
  }
  // 2) MFMA k-feature + partial kv/ksum (v4: 2 blocks/CU)
  kv_mfma_kernel<<<dim3(NCHUNK, 64), 256, 0, stream>>>(qkv, projT, partial);
  // 3) reduce partials
  kv_reduce_kernel<<<dim3(64*NF*KVS/256), 256, 0, stream>>>(partial, kvbuf);
  // 4) woutT (into region freed by reduce)
  transpose_cast<<<dim3(DIM_/32, DIM_/32, 1), 256, 0, stream>>>(w_out, woutT, DIM_, DIM_);
  // 5) MFMA q-feature + q'@kv + normalize -> attn bf16
  q_attn_mfma_kernel<<<dim3(NCHUNK, 64), 256, 0, stream>>>(qkv, projT, kvbuf, attn);
  // 6) out = attn @ w_out + b_out
  gemm256<true, float><<<256, 512, 0, stream>>>(attn, woutT, b_out, out, TOK, DIM_, DIM_, DIM_);
}